// Round 1
// baseline (17749.002 us; speedup 1.0000x reference)
//
#include <hip/hip_runtime.h>
#include <math.h>

// ---------------------------------------------------------------------------
// DETR-style transformer, f32 baseline.
// B=4, S_enc=1024, NQ=100, D=512, H=8, dk=64, FF=2048, L=6
// ---------------------------------------------------------------------------

// [B][C][S] -> [B][S][C], C=512, S=1024
__global__ __launch_bounds__(256) void k_transpose(const float* __restrict__ in,
                                                   float* __restrict__ out) {
  __shared__ float tile[32][33];
  int b = blockIdx.z;
  int c0 = blockIdx.x * 32, s0 = blockIdx.y * 32;
  int tx = threadIdx.x, ty = threadIdx.y;  // (32, 8)
  #pragma unroll
  for (int i = ty; i < 32; i += 8)
    tile[i][tx] = in[((size_t)(b * 512 + c0 + i)) * 1024 + s0 + tx];
  __syncthreads();
  #pragma unroll
  for (int i = ty; i < 32; i += 8)
    out[((size_t)(b * 1024 + s0 + i)) * 512 + c0 + tx] = tile[tx][i];
}

__global__ void k_add(const float* __restrict__ a, const float* __restrict__ b,
                      float* __restrict__ o, int n4) {
  int i = blockIdx.x * blockDim.x + threadIdx.x;
  if (i < n4) {
    float4 x = ((const float4*)a)[i];
    float4 y = ((const float4*)b)[i];
    ((float4*)o)[i] = make_float4(x.x + y.x, x.y + y.y, x.z + y.z, x.w + y.w);
  }
}

__global__ void k_zero(float* __restrict__ o, int n4) {
  int i = blockIdx.x * blockDim.x + threadIdx.x;
  if (i < n4) ((float4*)o)[i] = make_float4(0.f, 0.f, 0.f, 0.f);
}

__global__ void k_copy(const float* __restrict__ a, float* __restrict__ o, int n4) {
  int i = blockIdx.x * blockDim.x + threadIdx.x;
  if (i < n4) ((float4*)o)[i] = ((const float4*)a)[i];
}

// o[(b*100+q)*512+d] = a[...] + qe[q*512+d]; n4 = 51200 float4
__global__ void k_add_qe(const float* __restrict__ a, const float* __restrict__ qe,
                         float* __restrict__ o) {
  int i = blockIdx.x * blockDim.x + threadIdx.x;
  if (i < 51200) {
    int row = i >> 7;       // 128 float4 per row
    int q = row % 100;
    int c4 = i & 127;
    float4 x = ((const float4*)a)[i];
    float4 y = ((const float4*)qe)[q * 128 + c4];
    ((float4*)o)[i] = make_float4(x.x + y.x, x.y + y.y, x.z + y.z, x.w + y.w);
  }
}

// out = LN(a + b) * g + be ; one wave (64 lanes) per row of 512
__global__ __launch_bounds__(256) void k_ln_add(const float* __restrict__ A,
                                                const float* __restrict__ Bb,
                                                const float* __restrict__ g,
                                                const float* __restrict__ be,
                                                float* __restrict__ out, int rows) {
  int row = blockIdx.x * 4 + (threadIdx.x >> 6);
  int lane = threadIdx.x & 63;
  if (row >= rows) return;
  const float* pa = A + (size_t)row * 512;
  const float* pb = Bb + (size_t)row * 512;
  float v[8];
  float s = 0.f, s2 = 0.f;
  #pragma unroll
  for (int j = 0; j < 8; ++j) {
    float x = pa[lane + j * 64] + pb[lane + j * 64];
    v[j] = x; s += x; s2 += x * x;
  }
  #pragma unroll
  for (int off = 32; off > 0; off >>= 1) {
    s += __shfl_xor(s, off);
    s2 += __shfl_xor(s2, off);
  }
  float mean = s * (1.f / 512.f);
  float var = s2 * (1.f / 512.f) - mean * mean;
  float r = rsqrtf(var + 1e-5f);
  #pragma unroll
  for (int j = 0; j < 8; ++j) {
    int c = lane + j * 64;
    out[(size_t)row * 512 + c] = (v[j] - mean) * r * g[c] + be[c];
  }
}

// C[M,N] = A[M,K] @ W[K,N] + bias[N], optional relu.
// 128x128 tile, BK=16, 256 threads, 8x8 per thread (4+4 split halves).
__global__ __launch_bounds__(256) void k_gemm(const float* __restrict__ A,
                                              const float* __restrict__ W,
                                              const float* __restrict__ bias,
                                              float* __restrict__ C,
                                              int M, int N, int K, int relu) {
  __shared__ float As[16][129];
  __shared__ float Ws[16][129];
  int bm = blockIdx.y * 128, bn = blockIdx.x * 128;
  int t = threadIdx.x;
  int tx = t & 15, ty = t >> 4;
  float acc[8][8];
  #pragma unroll
  for (int i = 0; i < 8; ++i)
    #pragma unroll
    for (int j = 0; j < 8; ++j) acc[i][j] = 0.f;

  for (int k0 = 0; k0 < K; k0 += 16) {
    #pragma unroll
    for (int i = 0; i < 2; ++i) {
      int e = t + i * 256;                // 0..511 float4s
      int row = e >> 2, c4 = (e & 3) * 4;
      float4 v = make_float4(0.f, 0.f, 0.f, 0.f);
      if (bm + row < M) v = *(const float4*)(A + (size_t)(bm + row) * K + k0 + c4);
      As[c4 + 0][row] = v.x; As[c4 + 1][row] = v.y;
      As[c4 + 2][row] = v.z; As[c4 + 3][row] = v.w;
    }
    #pragma unroll
    for (int i = 0; i < 2; ++i) {
      int e = t + i * 256;
      int kk = e >> 5, n4 = (e & 31) * 4;
      *(float4*)&Ws[kk][n4] = *(const float4*)(W + (size_t)(k0 + kk) * N + bn + n4);
    }
    __syncthreads();
    #pragma unroll
    for (int kk = 0; kk < 16; ++kk) {
      float4 a0 = *(const float4*)&As[kk][ty * 4];
      float4 a1 = *(const float4*)&As[kk][ty * 4 + 64];
      float4 w0 = *(const float4*)&Ws[kk][tx * 4];
      float4 w1 = *(const float4*)&Ws[kk][tx * 4 + 64];
      float a[8] = {a0.x, a0.y, a0.z, a0.w, a1.x, a1.y, a1.z, a1.w};
      float w[8] = {w0.x, w0.y, w0.z, w0.w, w1.x, w1.y, w1.z, w1.w};
      #pragma unroll
      for (int i = 0; i < 8; ++i)
        #pragma unroll
        for (int j = 0; j < 8; ++j) acc[i][j] += a[i] * w[j];
    }
    __syncthreads();
  }

  #pragma unroll
  for (int ih = 0; ih < 2; ++ih)
    #pragma unroll
    for (int i = 0; i < 4; ++i) {
      int row = bm + ih * 64 + ty * 4 + i;
      if (row >= M) continue;
      #pragma unroll
      for (int jh = 0; jh < 2; ++jh) {
        int col = bn + jh * 64 + tx * 4;
        float4 bv = *(const float4*)(bias + col);
        float4 o;
        o.x = acc[ih * 4 + i][jh * 4 + 0] + bv.x;
        o.y = acc[ih * 4 + i][jh * 4 + 1] + bv.y;
        o.z = acc[ih * 4 + i][jh * 4 + 2] + bv.z;
        o.w = acc[ih * 4 + i][jh * 4 + 3] + bv.w;
        if (relu) {
          o.x = fmaxf(o.x, 0.f); o.y = fmaxf(o.y, 0.f);
          o.z = fmaxf(o.z, 0.f); o.w = fmaxf(o.w, 0.f);
        }
        *(float4*)(C + (size_t)row * N + col) = o;
      }
    }
}

// Flash-style MHA. Q[(b*Sq+s)*512 + h*64 + d], K/V likewise; O same layout.
// One block per (b, h, 32 q-rows); KV chunks of 64; online softmax.
__global__ __launch_bounds__(256) void k_attn(const float* __restrict__ Q,
                                              const float* __restrict__ Km,
                                              const float* __restrict__ Vm,
                                              float* __restrict__ O,
                                              int Sq, int Sk) {
  __shared__ float Qs[32][65];
  __shared__ float Ks[64][65];
  __shared__ float Vs[64][65];
  __shared__ float Sm[32][65];
  __shared__ float rowm[32], rowl[32], rowf[32];
  const float scale = 0.125f;  // 1/sqrt(64)
  int b = blockIdx.z, h = blockIdx.y;
  int q0 = blockIdx.x * 32;
  int t = threadIdx.x;
  int tx = t & 15, ty = t >> 4;
  float oacc[2][4] = {{0.f, 0.f, 0.f, 0.f}, {0.f, 0.f, 0.f, 0.f}};
  if (t < 32) { rowm[t] = -1e30f; rowl[t] = 0.f; }
  #pragma unroll
  for (int i = 0; i < 2; ++i) {
    int e = t + i * 256;
    int r = e >> 4, c4 = (e & 15) * 4;
    float4 v = make_float4(0.f, 0.f, 0.f, 0.f);
    if (q0 + r < Sq)
      v = *(const float4*)(Q + ((size_t)(b * Sq + q0 + r)) * 512 + h * 64 + c4);
    *(float4*)&Qs[r][c4] = v;
  }
  __syncthreads();

  for (int k0 = 0; k0 < Sk; k0 += 64) {
    #pragma unroll
    for (int i = 0; i < 4; ++i) {
      int e = t + i * 256;
      int r = e >> 4, c4 = (e & 15) * 4;
      float4 kv = make_float4(0.f, 0.f, 0.f, 0.f);
      float4 vv = make_float4(0.f, 0.f, 0.f, 0.f);
      if (k0 + r < Sk) {
        size_t base = ((size_t)(b * Sk + k0 + r)) * 512 + h * 64 + c4;
        kv = *(const float4*)(Km + base);
        vv = *(const float4*)(Vm + base);
      }
      *(float4*)&Ks[r][c4] = kv;
      *(float4*)&Vs[r][c4] = vv;
    }
    __syncthreads();

    // S = Q K^T : rows {2ty, 2ty+1}, cols {4tx..4tx+3}
    float sv[2][4] = {{0.f, 0.f, 0.f, 0.f}, {0.f, 0.f, 0.f, 0.f}};
    #pragma unroll
    for (int dq = 0; dq < 16; ++dq) {
      float4 qa = *(const float4*)&Qs[ty * 2][dq * 4];
      float4 qb4 = *(const float4*)&Qs[ty * 2 + 1][dq * 4];
      #pragma unroll
      for (int j = 0; j < 4; ++j) {
        float4 kk4 = *(const float4*)&Ks[tx * 4 + j][dq * 4];
        sv[0][j] += qa.x * kk4.x + qa.y * kk4.y + qa.z * kk4.z + qa.w * kk4.w;
        sv[1][j] += qb4.x * kk4.x + qb4.y * kk4.y + qb4.z * kk4.z + qb4.w * kk4.w;
      }
    }
    #pragma unroll
    for (int r = 0; r < 2; ++r) {
      float4 o4;
      o4.x = (k0 + tx * 4 + 0 < Sk) ? sv[r][0] * scale : -1e30f;
      o4.y = (k0 + tx * 4 + 1 < Sk) ? sv[r][1] * scale : -1e30f;
      o4.z = (k0 + tx * 4 + 2 < Sk) ? sv[r][2] * scale : -1e30f;
      o4.w = (k0 + tx * 4 + 3 < Sk) ? sv[r][3] * scale : -1e30f;
      *(float4*)&Sm[ty * 2 + r][tx * 4] = o4;
    }
    __syncthreads();

    if (t < 32) {
      float m0 = rowm[t];
      float cm = -1e30f;
      #pragma unroll 8
      for (int k = 0; k < 64; ++k) cm = fmaxf(cm, Sm[t][k]);
      float nm = fmaxf(m0, cm);
      float f = __expf(m0 - nm);
      float ps = 0.f;
      #pragma unroll 8
      for (int k = 0; k < 64; ++k) {
        float pv = __expf(Sm[t][k] - nm);
        Sm[t][k] = pv;
        ps += pv;
      }
      rowl[t] = rowl[t] * f + ps;
      rowm[t] = nm;
      rowf[t] = f;
    }
    __syncthreads();

    float f0 = rowf[ty * 2], f1 = rowf[ty * 2 + 1];
    #pragma unroll
    for (int j = 0; j < 4; ++j) { oacc[0][j] *= f0; oacc[1][j] *= f1; }
    #pragma unroll
    for (int kq = 0; kq < 16; ++kq) {
      float4 p0 = *(const float4*)&Sm[ty * 2][kq * 4];
      float4 p1 = *(const float4*)&Sm[ty * 2 + 1][kq * 4];
      float p0a[4] = {p0.x, p0.y, p0.z, p0.w};
      float p1a[4] = {p1.x, p1.y, p1.z, p1.w};
      #pragma unroll
      for (int kk = 0; kk < 4; ++kk) {
        float4 v4 = *(const float4*)&Vs[kq * 4 + kk][tx * 4];
        oacc[0][0] += p0a[kk] * v4.x; oacc[0][1] += p0a[kk] * v4.y;
        oacc[0][2] += p0a[kk] * v4.z; oacc[0][3] += p0a[kk] * v4.w;
        oacc[1][0] += p1a[kk] * v4.x; oacc[1][1] += p1a[kk] * v4.y;
        oacc[1][2] += p1a[kk] * v4.z; oacc[1][3] += p1a[kk] * v4.w;
      }
    }
    __syncthreads();
  }

  int r0 = q0 + ty * 2;
  float inv0 = 1.f / rowl[ty * 2];
  float inv1 = 1.f / rowl[ty * 2 + 1];
  if (r0 < Sq) {
    float4 o = make_float4(oacc[0][0] * inv0, oacc[0][1] * inv0,
                           oacc[0][2] * inv0, oacc[0][3] * inv0);
    *(float4*)(O + ((size_t)(b * Sq + r0)) * 512 + h * 64 + tx * 4) = o;
  }
  if (r0 + 1 < Sq) {
    float4 o = make_float4(oacc[1][0] * inv1, oacc[1][1] * inv1,
                           oacc[1][2] * inv1, oacc[1][3] * inv1);
    *(float4*)(O + ((size_t)(b * Sq + r0 + 1)) * 512 + h * 64 + tx * 4) = o;
  }
}

// ---------------------------------------------------------------------------

extern "C" void kernel_launch(void* const* d_in, const int* in_sizes, int n_in,
                              void* d_out, int out_size, void* d_ws, size_t ws_size,
                              hipStream_t stream) {
  const float* src         = (const float*)d_in[0];
  const float* query_embed = (const float*)d_in[1];
  const float* pos_embed   = (const float*)d_in[2];
  const float* enc_attn_w  = (const float*)d_in[3];
  const float* enc_attn_b  = (const float*)d_in[4];
  const float* enc_w1      = (const float*)d_in[5];
  const float* enc_b1      = (const float*)d_in[6];
  const float* enc_w2      = (const float*)d_in[7];
  const float* enc_b2      = (const float*)d_in[8];
  const float* enc_ln_w    = (const float*)d_in[9];
  const float* enc_ln_b    = (const float*)d_in[10];
  const float* dec_sa_w    = (const float*)d_in[11];
  const float* dec_sa_b    = (const float*)d_in[12];
  const float* dec_ca_w    = (const float*)d_in[13];
  const float* dec_ca_b    = (const float*)d_in[14];
  const float* dec_w1      = (const float*)d_in[15];
  const float* dec_b1      = (const float*)d_in[16];
  const float* dec_w2      = (const float*)d_in[17];
  const float* dec_b2      = (const float*)d_in[18];
  const float* dec_ln_w    = (const float*)d_in[19];
  const float* dec_ln_b    = (const float*)d_in[20];
  float* out = (float*)d_out;

  const size_t ENC = 4UL * 1024 * 512;  // 2097152
  const size_t DEC = 4UL * 100 * 512;   // 204800
  float* p = (float*)d_ws;
  float* x     = p; p += ENC;   // residual stream / memory
  float* pos   = p; p += ENC;
  float* t1    = p; p += ENC;
  float* t2    = p; p += ENC;
  float* t3    = p; p += DEC;
  float* qb    = p; p += ENC;
  float* kb    = p; p += ENC;
  float* vb    = p; p += ENC;
  float* ao    = p; p += ENC;   // attention output
  float* mo    = p; p += ENC;   // projection / ffn output
  float* memin = p; p += ENC;   // memory + pos
  float* dstr  = p; p += DEC;   // decoder stream
  float* hb    = p;             // ffn hidden 4096x2048

  dim3 tb(32, 8);
  k_transpose<<<dim3(16, 32, 4), tb, 0, stream>>>(src, x);
  k_transpose<<<dim3(16, 32, 4), tb, 0, stream>>>(pos_embed, pos);

  // ----------------------------- encoder ----------------------------------
  for (int l = 0; l < 6; ++l) {
    const float* aw = enc_attn_w + (size_t)l * 4 * 512 * 512;
    const float* ab = enc_attn_b + (size_t)l * 4 * 512;
    k_add<<<2048, 256, 0, stream>>>(x, pos, t1, (int)(ENC / 4));
    k_gemm<<<dim3(4, 32), 256, 0, stream>>>(t1, aw,          ab,        qb, 4096, 512, 512, 0);
    k_gemm<<<dim3(4, 32), 256, 0, stream>>>(t1, aw + 262144, ab + 512,  kb, 4096, 512, 512, 0);
    k_gemm<<<dim3(4, 32), 256, 0, stream>>>(t1, aw + 524288, ab + 1024, vb, 4096, 512, 512, 0);
    k_attn<<<dim3(32, 8, 4), 256, 0, stream>>>(qb, kb, vb, ao, 1024, 1024);
    k_gemm<<<dim3(4, 32), 256, 0, stream>>>(ao, aw + 786432, ab + 1536, mo, 4096, 512, 512, 0);
    k_ln_add<<<1024, 256, 0, stream>>>(t1, mo, enc_ln_w + (size_t)(l * 2 + 0) * 512,
                                       enc_ln_b + (size_t)(l * 2 + 0) * 512, t2, 4096);
    k_gemm<<<dim3(16, 32), 256, 0, stream>>>(t2, enc_w1 + (size_t)l * 512 * 2048,
                                             enc_b1 + (size_t)l * 2048, hb, 4096, 2048, 512, 1);
    k_gemm<<<dim3(4, 32), 256, 0, stream>>>(hb, enc_w2 + (size_t)l * 2048 * 512,
                                            enc_b2 + (size_t)l * 512, mo, 4096, 512, 2048, 0);
    k_ln_add<<<1024, 256, 0, stream>>>(t2, mo, enc_ln_w + (size_t)(l * 2 + 1) * 512,
                                       enc_ln_b + (size_t)(l * 2 + 1) * 512, x, 4096);
  }

  k_add<<<2048, 256, 0, stream>>>(x, pos, memin, (int)(ENC / 4));
  k_zero<<<200, 256, 0, stream>>>(dstr, (int)(DEC / 4));

  // ----------------------------- decoder ----------------------------------
  for (int l = 0; l < 6; ++l) {
    const float* sw = dec_sa_w + (size_t)l * 4 * 512 * 512;
    const float* sb = dec_sa_b + (size_t)l * 4 * 512;
    const float* cw = dec_ca_w + (size_t)l * 4 * 512 * 512;
    const float* cb = dec_ca_b + (size_t)l * 4 * 512;
    k_add_qe<<<200, 256, 0, stream>>>(dstr, query_embed, t1);
    // self-attention
    k_gemm<<<dim3(4, 4), 256, 0, stream>>>(t1, sw,          sb,        qb, 400, 512, 512, 0);
    k_gemm<<<dim3(4, 4), 256, 0, stream>>>(t1, sw + 262144, sb + 512,  kb, 400, 512, 512, 0);
    k_gemm<<<dim3(4, 4), 256, 0, stream>>>(t1, sw + 524288, sb + 1024, vb, 400, 512, 512, 0);
    k_attn<<<dim3(4, 8, 4), 256, 0, stream>>>(qb, kb, vb, ao, 100, 100);
    k_gemm<<<dim3(4, 4), 256, 0, stream>>>(ao, sw + 786432, sb + 1536, mo, 400, 512, 512, 0);
    k_ln_add<<<100, 256, 0, stream>>>(t1, mo, dec_ln_w + (size_t)(l * 3 + 0) * 512,
                                      dec_ln_b + (size_t)(l * 3 + 0) * 512, t2, 400);
    // cross-attention
    k_gemm<<<dim3(4, 4), 256, 0, stream>>>(t2, cw,           cb,        qb, 400, 512, 512, 0);
    k_gemm<<<dim3(4, 32), 256, 0, stream>>>(memin, cw + 262144, cb + 512,  kb, 4096, 512, 512, 0);
    k_gemm<<<dim3(4, 32), 256, 0, stream>>>(memin, cw + 524288, cb + 1024, vb, 4096, 512, 512, 0);
    k_attn<<<dim3(4, 8, 4), 256, 0, stream>>>(qb, kb, vb, ao, 100, 1024);
    k_gemm<<<dim3(4, 4), 256, 0, stream>>>(ao, cw + 786432, cb + 1536, mo, 400, 512, 512, 0);
    k_ln_add<<<100, 256, 0, stream>>>(t2, mo, dec_ln_w + (size_t)(l * 3 + 1) * 512,
                                      dec_ln_b + (size_t)(l * 3 + 1) * 512, t3, 400);
    // ffn
    k_gemm<<<dim3(16, 4), 256, 0, stream>>>(t3, dec_w1 + (size_t)l * 512 * 2048,
                                            dec_b1 + (size_t)l * 2048, hb, 400, 2048, 512, 1);
    k_gemm<<<dim3(4, 4), 256, 0, stream>>>(hb, dec_w2 + (size_t)l * 2048 * 512,
                                           dec_b2 + (size_t)l * 512, mo, 400, 512, 2048, 0);
    k_ln_add<<<100, 256, 0, stream>>>(t3, mo, dec_ln_w + (size_t)(l * 3 + 2) * 512,
                                      dec_ln_b + (size_t)(l * 3 + 2) * 512, dstr, 400);
  }

  // outputs: (decoder output, memory) concatenated
  k_copy<<<200, 256, 0, stream>>>(dstr, out, (int)(DEC / 4));
  k_copy<<<2048, 256, 0, stream>>>(x, out + DEC, (int)(ENC / 4));
}

// Round 2
// 4481.635 us; speedup vs baseline: 3.9604x; 3.9604x over previous
//
#include <hip/hip_runtime.h>
#include <math.h>

// ---------------------------------------------------------------------------
// DETR-style transformer. bf16 MFMA GEMMs + f32-compute flash attention.
// B=4, S_enc=1024, NQ=100, D=512, H=8, dk=64, FF=2048, L=6
// ---------------------------------------------------------------------------

typedef unsigned short bfu;
typedef unsigned int u32;
typedef __bf16 bf8v __attribute__((ext_vector_type(8)));
typedef float f32x4 __attribute__((ext_vector_type(4)));

__device__ inline bfu f2bf(float f) {
  union { float f; u32 u; } v; v.f = f;
  u32 u = v.u;
  u32 r = (u + 0x7fffu + ((u >> 16) & 1u)) >> 16;
  return (bfu)r;
}
__device__ inline float bflo(u32 u) { return __uint_as_float(u << 16); }
__device__ inline float bfhi(u32 u) { return __uint_as_float(u & 0xffff0000u); }

// ---------------- transpose f32 [B][C][S] -> [B][S][C] ----------------------
__global__ __launch_bounds__(256) void k_transpose(const float* __restrict__ in,
                                                   float* __restrict__ out) {
  __shared__ float tile[32][33];
  int b = blockIdx.z;
  int c0 = blockIdx.x * 32, s0 = blockIdx.y * 32;
  int tx = threadIdx.x, ty = threadIdx.y;  // (32, 8)
  for (int i = ty; i < 32; i += 8)
    tile[i][tx] = in[((size_t)(b * 512 + c0 + i)) * 1024 + s0 + tx];
  __syncthreads();
  for (int i = ty; i < 32; i += 8)
    out[((size_t)(b * 1024 + s0 + i)) * 512 + c0 + tx] = tile[tx][i];
}

// ---------------- weight transpose+convert: src f32 [K][N] -> dst bf16 [N][K]
// blockIdx.z = global mat g; l = g/nj, j = g%nj; src mat = (l*lstride + j)
__global__ __launch_bounds__(256) void k_wt(const float* __restrict__ src,
                                            bfu* __restrict__ dst,
                                            int K, int N, int nj, int lstride) {
  __shared__ bfu tile[32][33];
  int g = blockIdx.z;
  int l = g / nj, j = g - l * nj;
  const float* s = src + ((size_t)l * lstride + j) * (size_t)K * N;
  bfu* d = dst + (size_t)g * (size_t)K * N;
  int n0 = blockIdx.x * 32, k0 = blockIdx.y * 32;
  int tx = threadIdx.x, ty = threadIdx.y;  // (32, 8)
  for (int i = ty; i < 32; i += 8)
    tile[i][tx] = f2bf(s[(size_t)(k0 + i) * N + n0 + tx]);
  __syncthreads();
  for (int i = ty; i < 32; i += 8)
    d[(size_t)(n0 + i) * K + k0 + tx] = tile[tx][i];
}

// ---------------- elementwise adds --------------------------------------
__global__ void k_add_dual(const float* __restrict__ a, const float* __restrict__ b,
                           float* __restrict__ of, bfu* __restrict__ ob, int n4) {
  int i = blockIdx.x * blockDim.x + threadIdx.x;
  if (i >= n4) return;
  float4 x = ((const float4*)a)[i];
  float4 y = ((const float4*)b)[i];
  float4 r = make_float4(x.x + y.x, x.y + y.y, x.z + y.z, x.w + y.w);
  if (of) ((float4*)of)[i] = r;
  if (ob) ((ushort4*)ob)[i] = make_ushort4(f2bf(r.x), f2bf(r.y), f2bf(r.z), f2bf(r.w));
}

// dstr[(b*100+q)*512+d] + qe[q*512+d]
__global__ void k_add_qe_dual(const float* __restrict__ a, const float* __restrict__ qe,
                              float* __restrict__ of, bfu* __restrict__ ob) {
  int i = blockIdx.x * blockDim.x + threadIdx.x;
  if (i >= 51200) return;
  int row = i >> 7;
  int q = row % 100;
  int c4 = i & 127;
  float4 x = ((const float4*)a)[i];
  float4 y = ((const float4*)qe)[q * 128 + c4];
  float4 r = make_float4(x.x + y.x, x.y + y.y, x.z + y.z, x.w + y.w);
  if (of) ((float4*)of)[i] = r;
  if (ob) ((ushort4*)ob)[i] = make_ushort4(f2bf(r.x), f2bf(r.y), f2bf(r.z), f2bf(r.w));
}

__global__ void k_zero(float* __restrict__ o, int n4) {
  int i = blockIdx.x * blockDim.x + threadIdx.x;
  if (i < n4) ((float4*)o)[i] = make_float4(0.f, 0.f, 0.f, 0.f);
}

__global__ void k_copy(const float* __restrict__ a, float* __restrict__ o, int n4) {
  int i = blockIdx.x * blockDim.x + threadIdx.x;
  if (i < n4) ((float4*)o)[i] = ((const float4*)a)[i];
}

// ---------------- LN(a_f32 + b_bf16) -> f32 (+ optional bf16) --------------
__global__ __launch_bounds__(256) void k_ln(const float* __restrict__ A,
                                            const bfu* __restrict__ Bb,
                                            const float* __restrict__ g,
                                            const float* __restrict__ be,
                                            float* __restrict__ of,
                                            bfu* __restrict__ ob, int rows) {
  int row = blockIdx.x * 4 + (threadIdx.x >> 6);
  int lane = threadIdx.x & 63;
  if (row >= rows) return;
  const float* pa = A + (size_t)row * 512;
  const bfu* pb = Bb + (size_t)row * 512;
  float v[8];
  float s = 0.f, s2 = 0.f;
#pragma unroll
  for (int j = 0; j < 8; ++j) {
    int c = lane + j * 64;
    float x = pa[c] + bflo((u32)pb[c]);
    v[j] = x; s += x; s2 += x * x;
  }
#pragma unroll
  for (int off = 32; off > 0; off >>= 1) {
    s += __shfl_xor(s, off);
    s2 += __shfl_xor(s2, off);
  }
  float mean = s * (1.f / 512.f);
  float var = s2 * (1.f / 512.f) - mean * mean;
  float r = rsqrtf(var + 1e-5f);
#pragma unroll
  for (int j = 0; j < 8; ++j) {
    int c = lane + j * 64;
    float o = (v[j] - mean) * r * g[c] + be[c];
    of[(size_t)row * 512 + c] = o;
    if (ob) ob[(size_t)row * 512 + c] = f2bf(o);
  }
}

// ---------------- bf16 MFMA GEMM: C[M,N] = A[M,K] @ Wt[N,K]^T + bias -------
// 128x128 tile, BK=64, 256 threads = 4 waves (2x2), 4x4 16x16 frags per wave.
__global__ __launch_bounds__(256) void k_gemm_bf(const bfu* __restrict__ A,
                                                 const bfu* __restrict__ Wt,
                                                 const float* __restrict__ bias,
                                                 bfu* __restrict__ C,
                                                 int M, int N, int K, int relu) {
  __shared__ bfu As[128][72];
  __shared__ bfu Bs[128][72];
  int bm = blockIdx.y * 128, bn = blockIdx.x * 128;
  int t = threadIdx.x;
  int wave = t >> 6, lane = t & 63;
  int wm = wave >> 1, wn = wave & 1;
  int l15 = lane & 15, l4 = lane >> 4;
  f32x4 acc[4][4];
  f32x4 zz = {0.f, 0.f, 0.f, 0.f};
#pragma unroll
  for (int mi = 0; mi < 4; ++mi)
#pragma unroll
    for (int ni = 0; ni < 4; ++ni) acc[mi][ni] = zz;

  for (int k0 = 0; k0 < K; k0 += 64) {
#pragma unroll
    for (int i = 0; i < 4; ++i) {
      int c = t + i * 256;          // 0..1023
      int row = c >> 3, kg = c & 7;
      uint4 va = {0u, 0u, 0u, 0u};
      if (bm + row < M)
        va = *(const uint4*)(A + (size_t)(bm + row) * K + k0 + kg * 8);
      *(uint4*)&As[row][kg * 8] = va;
      uint4 vb = *(const uint4*)(Wt + (size_t)(bn + row) * K + k0 + kg * 8);
      *(uint4*)&Bs[row][kg * 8] = vb;
    }
    __syncthreads();
#pragma unroll
    for (int kc = 0; kc < 2; ++kc) {
      bf8v av[4], bv[4];
#pragma unroll
      for (int mi = 0; mi < 4; ++mi)
        av[mi] = *(const bf8v*)&As[wm * 64 + mi * 16 + l15][kc * 32 + l4 * 8];
#pragma unroll
      for (int ni = 0; ni < 4; ++ni)
        bv[ni] = *(const bf8v*)&Bs[wn * 64 + ni * 16 + l15][kc * 32 + l4 * 8];
#pragma unroll
      for (int mi = 0; mi < 4; ++mi)
#pragma unroll
        for (int ni = 0; ni < 4; ++ni)
          acc[mi][ni] = __builtin_amdgcn_mfma_f32_16x16x32_bf16(av[mi], bv[ni],
                                                                acc[mi][ni], 0, 0, 0);
    }
    __syncthreads();
  }

#pragma unroll
  for (int mi = 0; mi < 4; ++mi) {
    int row0 = bm + wm * 64 + mi * 16 + l4 * 4;
#pragma unroll
    for (int ni = 0; ni < 4; ++ni) {
      int col = bn + wn * 64 + ni * 16 + l15;
      float bb = bias[col];
#pragma unroll
      for (int r = 0; r < 4; ++r) {
        int row = row0 + r;
        if (row < M) {
          float v = acc[mi][ni][r] + bb;
          if (relu) v = fmaxf(v, 0.f);
          C[(size_t)row * N + col] = f2bf(v);
        }
      }
    }
  }
}

// ---------------- flash attention, bf16 in/out, f32 compute ----------------
// Q rows (b*Sq+q)*qs + h*64; K/V rows (b*Sk+k)*kvs + h*64; O stride 512.
// Block: 256 thr, 32 q-rows, kv chunks of 64. Parallel online softmax.
__global__ __launch_bounds__(256) void k_attn(const bfu* __restrict__ Q, int qs,
                                              const bfu* __restrict__ Km,
                                              const bfu* __restrict__ Vm, int kvs,
                                              bfu* __restrict__ O,
                                              int Sq, int Sk) {
  __shared__ float Qs[32][68];
  __shared__ float Ks[64][68];
  __shared__ float Vs[64][68];
  __shared__ float Sm[32][68];
  const float scale = 0.125f;
  int b = blockIdx.z, h = blockIdx.y;
  int q0 = blockIdx.x * 32;
  int t = threadIdx.x;
  int tx = t & 15, ty = t >> 4;
  int hoff = h * 64;

  {  // stage Q (zeros for OOB rows)
    int r = t >> 3, dg = t & 7;
    uint4 u = {0u, 0u, 0u, 0u};
    if (q0 + r < Sq)
      u = *(const uint4*)(Q + ((size_t)(b * Sq + q0 + r)) * qs + hoff + dg * 8);
    float* d = &Qs[r][dg * 8];
    d[0] = bflo(u.x); d[1] = bfhi(u.x); d[2] = bflo(u.y); d[3] = bfhi(u.y);
    d[4] = bflo(u.z); d[5] = bfhi(u.z); d[6] = bflo(u.w); d[7] = bfhi(u.w);
  }

  float m[2] = {-1e30f, -1e30f};
  float l[2] = {0.f, 0.f};
  float oacc[2][4] = {{0.f, 0.f, 0.f, 0.f}, {0.f, 0.f, 0.f, 0.f}};

  for (int k0 = 0; k0 < Sk; k0 += 64) {
#pragma unroll
    for (int i = 0; i < 2; ++i) {
      int c = t + i * 256;
      int r = c >> 3, dg = c & 7;
      uint4 uk = {0u, 0u, 0u, 0u}, uv = {0u, 0u, 0u, 0u};
      if (k0 + r < Sk) {
        size_t base = ((size_t)(b * Sk + k0 + r)) * kvs + hoff + dg * 8;
        uk = *(const uint4*)(Km + base);
        uv = *(const uint4*)(Vm + base);
      }
      float* dk = &Ks[r][dg * 8];
      dk[0] = bflo(uk.x); dk[1] = bfhi(uk.x); dk[2] = bflo(uk.y); dk[3] = bfhi(uk.y);
      dk[4] = bflo(uk.z); dk[5] = bfhi(uk.z); dk[6] = bflo(uk.w); dk[7] = bfhi(uk.w);
      float* dv = &Vs[r][dg * 8];
      dv[0] = bflo(uv.x); dv[1] = bfhi(uv.x); dv[2] = bflo(uv.y); dv[3] = bfhi(uv.y);
      dv[4] = bflo(uv.z); dv[5] = bfhi(uv.z); dv[6] = bflo(uv.w); dv[7] = bfhi(uv.w);
    }
    __syncthreads();  // (1)

    // S rows {2ty,2ty+1} x cols {tx+16j}
    float sv[2][4] = {{0.f, 0.f, 0.f, 0.f}, {0.f, 0.f, 0.f, 0.f}};
#pragma unroll
    for (int dq = 0; dq < 16; ++dq) {
      float4 qa = *(const float4*)&Qs[2 * ty][dq * 4];
      float4 qb = *(const float4*)&Qs[2 * ty + 1][dq * 4];
#pragma unroll
      for (int j = 0; j < 4; ++j) {
        float4 kk = *(const float4*)&Ks[tx + 16 * j][dq * 4];
        sv[0][j] += qa.x * kk.x + qa.y * kk.y + qa.z * kk.z + qa.w * kk.w;
        sv[1][j] += qb.x * kk.x + qb.y * kk.y + qb.z * kk.z + qb.w * kk.w;
      }
    }
#pragma unroll
    for (int r = 0; r < 2; ++r)
#pragma unroll
      for (int j = 0; j < 4; ++j) {
        float s = sv[r][j] * scale;
        sv[r][j] = (k0 + tx + 16 * j < Sk) ? s : -1e30f;
      }

    // online softmax, fully in registers (16-lane row groups)
#pragma unroll
    for (int r = 0; r < 2; ++r) {
      float cm = fmaxf(fmaxf(sv[r][0], sv[r][1]), fmaxf(sv[r][2], sv[r][3]));
#pragma unroll
      for (int off = 1; off < 16; off <<= 1) cm = fmaxf(cm, __shfl_xor(cm, off));
      float nm = fmaxf(m[r], cm);
      float f = __expf(m[r] - nm);
      float p[4], ps = 0.f;
#pragma unroll
      for (int j = 0; j < 4; ++j) { p[j] = __expf(sv[r][j] - nm); ps += p[j]; }
#pragma unroll
      for (int off = 1; off < 16; off <<= 1) ps += __shfl_xor(ps, off);
      l[r] = l[r] * f + ps;
      m[r] = nm;
#pragma unroll
      for (int j = 0; j < 4; ++j) {
        oacc[r][j] *= f;
        Sm[2 * ty + r][tx + 16 * j] = p[j];
      }
    }
    __syncthreads();  // (2)

    // O += P @ V : rows {2ty,2ty+1}, d-cols {4tx..4tx+3}
#pragma unroll
    for (int kq = 0; kq < 16; ++kq) {
      float4 p0 = *(const float4*)&Sm[2 * ty][kq * 4];
      float4 p1 = *(const float4*)&Sm[2 * ty + 1][kq * 4];
      float p0a[4] = {p0.x, p0.y, p0.z, p0.w};
      float p1a[4] = {p1.x, p1.y, p1.z, p1.w};
#pragma unroll
      for (int kk = 0; kk < 4; ++kk) {
        float4 v4 = *(const float4*)&Vs[kq * 4 + kk][tx * 4];
        oacc[0][0] += p0a[kk] * v4.x; oacc[0][1] += p0a[kk] * v4.y;
        oacc[0][2] += p0a[kk] * v4.z; oacc[0][3] += p0a[kk] * v4.w;
        oacc[1][0] += p1a[kk] * v4.x; oacc[1][1] += p1a[kk] * v4.y;
        oacc[1][2] += p1a[kk] * v4.z; oacc[1][3] += p1a[kk] * v4.w;
      }
    }
    __syncthreads();  // (3)
  }

#pragma unroll
  for (int r = 0; r < 2; ++r) {
    int row = q0 + 2 * ty + r;
    if (row < Sq) {
      float inv = 1.f / l[r];
      ushort4 o = make_ushort4(f2bf(oacc[r][0] * inv), f2bf(oacc[r][1] * inv),
                               f2bf(oacc[r][2] * inv), f2bf(oacc[r][3] * inv));
      *(ushort4*)(O + ((size_t)(b * Sq + row)) * 512 + hoff + tx * 4) = o;
    }
  }
}

// ---------------------------------------------------------------------------

extern "C" void kernel_launch(void* const* d_in, const int* in_sizes, int n_in,
                              void* d_out, int out_size, void* d_ws, size_t ws_size,
                              hipStream_t stream) {
  const float* src         = (const float*)d_in[0];
  const float* query_embed = (const float*)d_in[1];
  const float* pos_embed   = (const float*)d_in[2];
  const float* enc_attn_w  = (const float*)d_in[3];
  const float* enc_attn_b  = (const float*)d_in[4];
  const float* enc_w1      = (const float*)d_in[5];
  const float* enc_b1      = (const float*)d_in[6];
  const float* enc_w2      = (const float*)d_in[7];
  const float* enc_b2      = (const float*)d_in[8];
  const float* enc_ln_w    = (const float*)d_in[9];
  const float* enc_ln_b    = (const float*)d_in[10];
  const float* dec_sa_w    = (const float*)d_in[11];
  const float* dec_sa_b    = (const float*)d_in[12];
  const float* dec_ca_w    = (const float*)d_in[13];
  const float* dec_ca_b    = (const float*)d_in[14];
  const float* dec_w1      = (const float*)d_in[15];
  const float* dec_b1      = (const float*)d_in[16];
  const float* dec_w2      = (const float*)d_in[17];
  const float* dec_b2      = (const float*)d_in[18];
  const float* dec_ln_w    = (const float*)d_in[19];
  const float* dec_ln_b    = (const float*)d_in[20];
  float* out = (float*)d_out;

  const size_t ENC = 4UL * 1024 * 512;   // 2097152
  const size_t DEC = 4UL * 100 * 512;    // 204800
  const size_t MAT = 512UL * 512;        // 262144

  float* p = (float*)d_ws;
  float* x    = p; p += ENC;
  float* pos  = p; p += ENC;
  float* t1   = p; p += ENC;
  float* t2   = p; p += ENC;
  float* t3   = p; p += DEC;
  float* dstr = p; p += DEC;

  bfu* bp = (bfu*)p;
  bfu* t1b    = bp; bp += ENC;
  bfu* t2b    = bp; bp += ENC;
  bfu* t3b    = bp; bp += DEC;
  bfu* qkvb   = bp; bp += 4096UL * 1536;
  bfu* aob    = bp; bp += ENC;
  bfu* mob    = bp; bp += ENC;
  bfu* hbb    = bp; bp += 4096UL * 2048;
  bfu* meminb = bp; bp += ENC;
  bfu* ckvb   = bp; bp += 4096UL * 1024;
  // transposed bf16 weights
  bfu* enc_qkv_t = bp; bp += 18 * MAT;
  bfu* enc_out_t = bp; bp += 6 * MAT;
  bfu* enc_w1t   = bp; bp += 6UL * 512 * 2048;
  bfu* enc_w2t   = bp; bp += 6UL * 2048 * 512;
  bfu* dsa_qkv_t = bp; bp += 18 * MAT;
  bfu* dsa_out_t = bp; bp += 6 * MAT;
  bfu* dca_q_t   = bp; bp += 6 * MAT;
  bfu* dca_kv_t  = bp; bp += 12 * MAT;
  bfu* dca_out_t = bp; bp += 6 * MAT;
  bfu* dw1t      = bp; bp += 6UL * 512 * 2048;
  bfu* dw2t      = bp; bp += 6UL * 2048 * 512;

  dim3 tb(32, 8);
  k_transpose<<<dim3(16, 32, 4), tb, 0, stream>>>(src, x);
  k_transpose<<<dim3(16, 32, 4), tb, 0, stream>>>(pos_embed, pos);

  // weight conversion (once per launch)
  k_wt<<<dim3(16, 16, 18), tb, 0, stream>>>(enc_attn_w,            enc_qkv_t, 512, 512, 3, 4);
  k_wt<<<dim3(16, 16, 6),  tb, 0, stream>>>(enc_attn_w + 3 * MAT,  enc_out_t, 512, 512, 1, 4);
  k_wt<<<dim3(64, 16, 6),  tb, 0, stream>>>(enc_w1,                enc_w1t,   512, 2048, 1, 1);
  k_wt<<<dim3(16, 64, 6),  tb, 0, stream>>>(enc_w2,                enc_w2t,   2048, 512, 1, 1);
  k_wt<<<dim3(16, 16, 18), tb, 0, stream>>>(dec_sa_w,              dsa_qkv_t, 512, 512, 3, 4);
  k_wt<<<dim3(16, 16, 6),  tb, 0, stream>>>(dec_sa_w + 3 * MAT,    dsa_out_t, 512, 512, 1, 4);
  k_wt<<<dim3(16, 16, 6),  tb, 0, stream>>>(dec_ca_w,              dca_q_t,   512, 512, 1, 4);
  k_wt<<<dim3(16, 16, 12), tb, 0, stream>>>(dec_ca_w + 1 * MAT,    dca_kv_t,  512, 512, 2, 4);
  k_wt<<<dim3(16, 16, 6),  tb, 0, stream>>>(dec_ca_w + 3 * MAT,    dca_out_t, 512, 512, 1, 4);
  k_wt<<<dim3(64, 16, 6),  tb, 0, stream>>>(dec_w1,                dw1t,      512, 2048, 1, 1);
  k_wt<<<dim3(16, 64, 6),  tb, 0, stream>>>(dec_w2,                dw2t,      2048, 512, 1, 1);

  // ----------------------------- encoder ----------------------------------
  for (int l = 0; l < 6; ++l) {
    const float* ab = enc_attn_b + (size_t)l * 2048;
    k_add_dual<<<2048, 256, 0, stream>>>(x, pos, t1, t1b, (int)(ENC / 4));
    k_gemm_bf<<<dim3(12, 32), 256, 0, stream>>>(t1b, enc_qkv_t + (size_t)l * 3 * MAT, ab,
                                                qkvb, 4096, 1536, 512, 0);
    k_attn<<<dim3(32, 8, 4), 256, 0, stream>>>(qkvb, 1536, qkvb + 512, qkvb + 1024, 1536,
                                               aob, 1024, 1024);
    k_gemm_bf<<<dim3(4, 32), 256, 0, stream>>>(aob, enc_out_t + (size_t)l * MAT, ab + 1536,
                                               mob, 4096, 512, 512, 0);
    k_ln<<<1024, 256, 0, stream>>>(t1, mob, enc_ln_w + (size_t)(l * 2 + 0) * 512,
                                   enc_ln_b + (size_t)(l * 2 + 0) * 512, t2, t2b, 4096);
    k_gemm_bf<<<dim3(16, 32), 256, 0, stream>>>(t2b, enc_w1t + (size_t)l * 512 * 2048,
                                                enc_b1 + (size_t)l * 2048, hbb,
                                                4096, 2048, 512, 1);
    k_gemm_bf<<<dim3(4, 32), 256, 0, stream>>>(hbb, enc_w2t + (size_t)l * 2048 * 512,
                                               enc_b2 + (size_t)l * 512, mob,
                                               4096, 512, 2048, 0);
    k_ln<<<1024, 256, 0, stream>>>(t2, mob, enc_ln_w + (size_t)(l * 2 + 1) * 512,
                                   enc_ln_b + (size_t)(l * 2 + 1) * 512, x, (bfu*)nullptr, 4096);
  }

  k_add_dual<<<2048, 256, 0, stream>>>(x, pos, (float*)nullptr, meminb, (int)(ENC / 4));
  k_zero<<<200, 256, 0, stream>>>(dstr, (int)(DEC / 4));

  // ----------------------------- decoder ----------------------------------
  for (int l = 0; l < 6; ++l) {
    const float* sb = dec_sa_b + (size_t)l * 2048;
    const float* cb = dec_ca_b + (size_t)l * 2048;
    k_add_qe_dual<<<200, 256, 0, stream>>>(dstr, query_embed, t1, t1b);
    // self-attention
    k_gemm_bf<<<dim3(12, 4), 256, 0, stream>>>(t1b, dsa_qkv_t + (size_t)l * 3 * MAT, sb,
                                               qkvb, 400, 1536, 512, 0);
    k_attn<<<dim3(4, 8, 4), 256, 0, stream>>>(qkvb, 1536, qkvb + 512, qkvb + 1024, 1536,
                                              aob, 100, 100);
    k_gemm_bf<<<dim3(4, 4), 256, 0, stream>>>(aob, dsa_out_t + (size_t)l * MAT, sb + 1536,
                                              mob, 400, 512, 512, 0);
    k_ln<<<100, 256, 0, stream>>>(t1, mob, dec_ln_w + (size_t)(l * 3 + 0) * 512,
                                  dec_ln_b + (size_t)(l * 3 + 0) * 512, t2, t2b, 400);
    // cross-attention
    k_gemm_bf<<<dim3(4, 4), 256, 0, stream>>>(t2b, dca_q_t + (size_t)l * MAT, cb,
                                              qkvb, 400, 512, 512, 0);
    k_gemm_bf<<<dim3(8, 32), 256, 0, stream>>>(meminb, dca_kv_t + (size_t)l * 2 * MAT, cb + 512,
                                               ckvb, 4096, 1024, 512, 0);
    k_attn<<<dim3(4, 8, 4), 256, 0, stream>>>(qkvb, 512, ckvb, ckvb + 512, 1024,
                                              aob, 100, 1024);
    k_gemm_bf<<<dim3(4, 4), 256, 0, stream>>>(aob, dca_out_t + (size_t)l * MAT, cb + 1536,
                                              mob, 400, 512, 512, 0);
    k_ln<<<100, 256, 0, stream>>>(t2, mob, dec_ln_w + (size_t)(l * 3 + 1) * 512,
                                  dec_ln_b + (size_t)(l * 3 + 1) * 512, t3, t3b, 400);
    // ffn
    k_gemm_bf<<<dim3(16, 4), 256, 0, stream>>>(t3b, dw1t + (size_t)l * 512 * 2048,
                                               dec_b1 + (size_t)l * 2048, hbb,
                                               400, 2048, 512, 1);
    k_gemm_bf<<<dim3(4, 4), 256, 0, stream>>>(hbb, dw2t + (size_t)l * 2048 * 512,
                                              dec_b2 + (size_t)l * 512, mob,
                                              400, 512, 2048, 0);
    k_ln<<<100, 256, 0, stream>>>(t3, mob, dec_ln_w + (size_t)(l * 3 + 2) * 512,
                                  dec_ln_b + (size_t)(l * 3 + 2) * 512, dstr, (bfu*)nullptr, 400);
  }

  k_copy<<<200, 256, 0, stream>>>(dstr, out, (int)(DEC / 4));
  k_copy<<<2048, 256, 0, stream>>>(x, out + DEC, (int)(ENC / 4));
}

// Round 3
// 3058.767 us; speedup vs baseline: 5.8027x; 1.4652x over previous
//
#include <hip/hip_runtime.h>
#include <math.h>

// ---------------------------------------------------------------------------
// DETR-style transformer. bf16 MFMA GEMMs + bf16 MFMA flash attention.
// B=4, S_enc=1024, NQ=100, D=512, H=8, dk=64, FF=2048, L=6
// ---------------------------------------------------------------------------

typedef unsigned short bfu;
typedef unsigned int u32;
typedef __bf16 bf8v __attribute__((ext_vector_type(8)));
typedef float f32x4 __attribute__((ext_vector_type(4)));

__device__ inline bfu f2bf(float f) {
  union { float f; u32 u; } v; v.f = f;
  u32 u = v.u;
  u32 r = (u + 0x7fffu + ((u >> 16) & 1u)) >> 16;
  return (bfu)r;
}
__device__ inline float bflo(u32 u) { return __uint_as_float(u << 16); }
__device__ inline float bfhi(u32 u) { return __uint_as_float(u & 0xffff0000u); }

// ---------------- transpose f32 [B][C][S] -> [B][S][C] ----------------------
__global__ __launch_bounds__(256) void k_transpose(const float* __restrict__ in,
                                                   float* __restrict__ out) {
  __shared__ float tile[32][33];
  int b = blockIdx.z;
  int c0 = blockIdx.x * 32, s0 = blockIdx.y * 32;
  int tx = threadIdx.x, ty = threadIdx.y;  // (32, 8)
  for (int i = ty; i < 32; i += 8)
    tile[i][tx] = in[((size_t)(b * 512 + c0 + i)) * 1024 + s0 + tx];
  __syncthreads();
  for (int i = ty; i < 32; i += 8)
    out[((size_t)(b * 1024 + s0 + i)) * 512 + c0 + tx] = tile[tx][i];
}

// ---------------- weight transpose+convert: src f32 [K][N] -> dst bf16 [N][K]
__global__ __launch_bounds__(256) void k_wt(const float* __restrict__ src,
                                            bfu* __restrict__ dst,
                                            int K, int N, int nj, int lstride) {
  __shared__ bfu tile[32][33];
  int g = blockIdx.z;
  int l = g / nj, j = g - l * nj;
  const float* s = src + ((size_t)l * lstride + j) * (size_t)K * N;
  bfu* d = dst + (size_t)g * (size_t)K * N;
  int n0 = blockIdx.x * 32, k0 = blockIdx.y * 32;
  int tx = threadIdx.x, ty = threadIdx.y;  // (32, 8)
  for (int i = ty; i < 32; i += 8)
    tile[i][tx] = f2bf(s[(size_t)(k0 + i) * N + n0 + tx]);
  __syncthreads();
  for (int i = ty; i < 32; i += 8)
    d[(size_t)(n0 + i) * K + k0 + tx] = tile[tx][i];
}

// ---------------- elementwise adds --------------------------------------
__global__ void k_add_dual(const float* __restrict__ a, const float* __restrict__ b,
                           float* __restrict__ of, bfu* __restrict__ ob, int n4) {
  int i = blockIdx.x * blockDim.x + threadIdx.x;
  if (i >= n4) return;
  float4 x = ((const float4*)a)[i];
  float4 y = ((const float4*)b)[i];
  float4 r = make_float4(x.x + y.x, x.y + y.y, x.z + y.z, x.w + y.w);
  if (of) ((float4*)of)[i] = r;
  if (ob) ((ushort4*)ob)[i] = make_ushort4(f2bf(r.x), f2bf(r.y), f2bf(r.z), f2bf(r.w));
}

__global__ void k_add_qe_dual(const float* __restrict__ a, const float* __restrict__ qe,
                              float* __restrict__ of, bfu* __restrict__ ob) {
  int i = blockIdx.x * blockDim.x + threadIdx.x;
  if (i >= 51200) return;
  int row = i >> 7;
  int q = row % 100;
  int c4 = i & 127;
  float4 x = ((const float4*)a)[i];
  float4 y = ((const float4*)qe)[q * 128 + c4];
  float4 r = make_float4(x.x + y.x, x.y + y.y, x.z + y.z, x.w + y.w);
  if (of) ((float4*)of)[i] = r;
  if (ob) ((ushort4*)ob)[i] = make_ushort4(f2bf(r.x), f2bf(r.y), f2bf(r.z), f2bf(r.w));
}

__global__ void k_zero(float* __restrict__ o, int n4) {
  int i = blockIdx.x * blockDim.x + threadIdx.x;
  if (i < n4) ((float4*)o)[i] = make_float4(0.f, 0.f, 0.f, 0.f);
}

__global__ void k_copy(const float* __restrict__ a, float* __restrict__ o, int n4) {
  int i = blockIdx.x * blockDim.x + threadIdx.x;
  if (i < n4) ((float4*)o)[i] = ((const float4*)a)[i];
}

// ---------------- LN(a_f32 + b_bf16) -> f32 (+ optional bf16) --------------
__global__ __launch_bounds__(256) void k_ln(const float* __restrict__ A,
                                            const bfu* __restrict__ Bb,
                                            const float* __restrict__ g,
                                            const float* __restrict__ be,
                                            float* __restrict__ of,
                                            bfu* __restrict__ ob, int rows) {
  int row = blockIdx.x * 4 + (threadIdx.x >> 6);
  int lane = threadIdx.x & 63;
  if (row >= rows) return;
  const float* pa = A + (size_t)row * 512;
  const bfu* pb = Bb + (size_t)row * 512;
  float v[8];
  float s = 0.f, s2 = 0.f;
#pragma unroll
  for (int j = 0; j < 8; ++j) {
    int c = lane + j * 64;
    float x = pa[c] + bflo((u32)pb[c]);
    v[j] = x; s += x; s2 += x * x;
  }
#pragma unroll
  for (int off = 32; off > 0; off >>= 1) {
    s += __shfl_xor(s, off);
    s2 += __shfl_xor(s2, off);
  }
  float mean = s * (1.f / 512.f);
  float var = s2 * (1.f / 512.f) - mean * mean;
  float r = rsqrtf(var + 1e-5f);
#pragma unroll
  for (int j = 0; j < 8; ++j) {
    int c = lane + j * 64;
    float o = (v[j] - mean) * r * g[c] + be[c];
    of[(size_t)row * 512 + c] = o;
    if (ob) ob[(size_t)row * 512 + c] = f2bf(o);
  }
}

// ---------------- bf16 MFMA GEMM: C[M,N] = A[M,K] @ Wt[N,K]^T + bias -------
__global__ __launch_bounds__(256) void k_gemm_bf(const bfu* __restrict__ A,
                                                 const bfu* __restrict__ Wt,
                                                 const float* __restrict__ bias,
                                                 bfu* __restrict__ C,
                                                 int M, int N, int K, int relu) {
  __shared__ bfu As[128][72];
  __shared__ bfu Bs[128][72];
  int bm = blockIdx.y * 128, bn = blockIdx.x * 128;
  int t = threadIdx.x;
  int wave = t >> 6, lane = t & 63;
  int wm = wave >> 1, wn = wave & 1;
  int l15 = lane & 15, l4 = lane >> 4;
  f32x4 acc[4][4];
  f32x4 zz = {0.f, 0.f, 0.f, 0.f};
#pragma unroll
  for (int mi = 0; mi < 4; ++mi)
#pragma unroll
    for (int ni = 0; ni < 4; ++ni) acc[mi][ni] = zz;

  for (int k0 = 0; k0 < K; k0 += 64) {
#pragma unroll
    for (int i = 0; i < 4; ++i) {
      int c = t + i * 256;          // 0..1023
      int row = c >> 3, kg = c & 7;
      uint4 va = {0u, 0u, 0u, 0u};
      if (bm + row < M)
        va = *(const uint4*)(A + (size_t)(bm + row) * K + k0 + kg * 8);
      *(uint4*)&As[row][kg * 8] = va;
      uint4 vb = *(const uint4*)(Wt + (size_t)(bn + row) * K + k0 + kg * 8);
      *(uint4*)&Bs[row][kg * 8] = vb;
    }
    __syncthreads();
#pragma unroll
    for (int kc = 0; kc < 2; ++kc) {
      bf8v av[4], bv[4];
#pragma unroll
      for (int mi = 0; mi < 4; ++mi)
        av[mi] = *(const bf8v*)&As[wm * 64 + mi * 16 + l15][kc * 32 + l4 * 8];
#pragma unroll
      for (int ni = 0; ni < 4; ++ni)
        bv[ni] = *(const bf8v*)&Bs[wn * 64 + ni * 16 + l15][kc * 32 + l4 * 8];
#pragma unroll
      for (int mi = 0; mi < 4; ++mi)
#pragma unroll
        for (int ni = 0; ni < 4; ++ni)
          acc[mi][ni] = __builtin_amdgcn_mfma_f32_16x16x32_bf16(av[mi], bv[ni],
                                                                acc[mi][ni], 0, 0, 0);
    }
    __syncthreads();
  }

#pragma unroll
  for (int mi = 0; mi < 4; ++mi) {
    int row0 = bm + wm * 64 + mi * 16 + l4 * 4;
#pragma unroll
    for (int ni = 0; ni < 4; ++ni) {
      int col = bn + wn * 64 + ni * 16 + l15;
      float bb = bias[col];
#pragma unroll
      for (int r = 0; r < 4; ++r) {
        int row = row0 + r;
        if (row < M) {
          float v = acc[mi][ni][r] + bb;
          if (relu) v = fmaxf(v, 0.f);
          C[(size_t)row * N + col] = f2bf(v);
        }
      }
    }
  }
}

// ---------------- MFMA flash attention ------------------------------------
// 256 thr = 4 waves; wave w owns q-rows [q0 + 16w, q0 + 16w + 16); KV chunk 64.
// Q rows (b*Sq+q)*qs + h*64; K/V rows (b*Sk+k)*kvs + h*64; O stride 512.
__global__ __launch_bounds__(256) void k_attn_mfma(const bfu* __restrict__ Q, int qs,
                                                   const bfu* __restrict__ Km,
                                                   const bfu* __restrict__ Vm, int kvs,
                                                   bfu* __restrict__ O,
                                                   int Sq, int Sk) {
  __shared__ bfu Ks[64][72];
  __shared__ bfu Vt[64][72];       // Vt[d][kv]
  __shared__ bfu Sm[4][16][72];    // per-wave P tile
  const float scale = 0.125f;
  int b = blockIdx.z, h = blockIdx.y;
  int q0 = blockIdx.x * 64;
  int t = threadIdx.x;
  int wave = t >> 6, lane = t & 63;
  int l15 = lane & 15, l4 = lane >> 4;
  int hoff = h * 64;

  // Q fragments in registers: A[row=l15][k = kc*32 + l4*8 + j]
  uint4 uq0 = {0u, 0u, 0u, 0u}, uq1 = {0u, 0u, 0u, 0u};
  {
    int qrow = q0 + wave * 16 + l15;
    if (qrow < Sq) {
      const bfu* qp = Q + (size_t)(b * Sq + qrow) * qs + hoff + l4 * 8;
      uq0 = *(const uint4*)qp;
      uq1 = *(const uint4*)(qp + 32);
    }
  }
  bf8v qf0 = *(bf8v*)&uq0, qf1 = *(bf8v*)&uq1;

  float m_[4] = {-1e30f, -1e30f, -1e30f, -1e30f};
  float l_[4] = {0.f, 0.f, 0.f, 0.f};
  f32x4 oacc[4];
  f32x4 zz = {0.f, 0.f, 0.f, 0.f};
#pragma unroll
  for (int n = 0; n < 4; ++n) oacc[n] = zz;

  for (int k0 = 0; k0 < Sk; k0 += 64) {
    // stage K (row-major) and V (transposed)
#pragma unroll
    for (int i = 0; i < 2; ++i) {
      int e = t + i * 256;            // K: 512 x uint4
      int r = e >> 3, cg = e & 7;
      uint4 uk = {0u, 0u, 0u, 0u};
      if (k0 + r < Sk)
        uk = *(const uint4*)(Km + (size_t)(b * Sk + k0 + r) * kvs + hoff + cg * 8);
      *(uint4*)&Ks[r][cg * 8] = uk;
    }
#pragma unroll
    for (int i = 0; i < 2; ++i) {
      int e = t + i * 256;            // V: lane kv, dgroup
      int kv = e & 63, dg = e >> 6;
      uint4 uv = {0u, 0u, 0u, 0u};
      if (k0 + kv < Sk)
        uv = *(const uint4*)(Vm + (size_t)(b * Sk + k0 + kv) * kvs + hoff + dg * 8);
      bfu vv[8];
      *(uint4*)vv = uv;
#pragma unroll
      for (int j = 0; j < 8; ++j) Vt[dg * 8 + j][kv] = vv[j];
    }
    __syncthreads();  // (1) tiles ready

    // S = Q K^T : 4 kv-tiles of 16
    f32x4 s4[4];
#pragma unroll
    for (int tt = 0; tt < 4; ++tt) {
      bf8v kf0 = *(const bf8v*)&Ks[tt * 16 + l15][l4 * 8];
      bf8v kf1 = *(const bf8v*)&Ks[tt * 16 + l15][32 + l4 * 8];
      f32x4 a = zz;
      a = __builtin_amdgcn_mfma_f32_16x16x32_bf16(qf0, kf0, a, 0, 0, 0);
      a = __builtin_amdgcn_mfma_f32_16x16x32_bf16(qf1, kf1, a, 0, 0, 0);
      s4[tt] = a;
    }

    // online softmax; lane sees q-rows l4*4+r, kv cols tt*16+l15
    float f_[4];
#pragma unroll
    for (int r = 0; r < 4; ++r) {
      float sv[4];
      float mx = -1e30f;
#pragma unroll
      for (int tt = 0; tt < 4; ++tt) {
        float s = s4[tt][r] * scale;
        s = (k0 + tt * 16 + l15 < Sk) ? s : -1e30f;
        sv[tt] = s;
        mx = fmaxf(mx, s);
      }
#pragma unroll
      for (int off = 1; off < 16; off <<= 1) mx = fmaxf(mx, __shfl_xor(mx, off));
      float nm = fmaxf(m_[r], mx);
      float f = __expf(m_[r] - nm);
      float ps = 0.f;
#pragma unroll
      for (int tt = 0; tt < 4; ++tt) {
        float p = __expf(sv[tt] - nm);
        ps += p;
        Sm[wave][l4 * 4 + r][tt * 16 + l15] = f2bf(p);
      }
#pragma unroll
      for (int off = 1; off < 16; off <<= 1) ps += __shfl_xor(ps, off);
      l_[r] = l_[r] * f + ps;
      m_[r] = nm;
      f_[r] = f;
    }
#pragma unroll
    for (int n = 0; n < 4; ++n)
#pragma unroll
      for (int r = 0; r < 4; ++r) oacc[n][r] *= f_[r];

    // O += P V : P rows=q (A row=l15), V cols = d (B col=l15)
    bf8v p0 = *(const bf8v*)&Sm[wave][l15][l4 * 8];
    bf8v p1 = *(const bf8v*)&Sm[wave][l15][32 + l4 * 8];
#pragma unroll
    for (int n = 0; n < 4; ++n) {
      bf8v v0 = *(const bf8v*)&Vt[n * 16 + l15][l4 * 8];
      bf8v v1 = *(const bf8v*)&Vt[n * 16 + l15][32 + l4 * 8];
      oacc[n] = __builtin_amdgcn_mfma_f32_16x16x32_bf16(p0, v0, oacc[n], 0, 0, 0);
      oacc[n] = __builtin_amdgcn_mfma_f32_16x16x32_bf16(p1, v1, oacc[n], 0, 0, 0);
    }
    __syncthreads();  // (2) done reading tiles
  }

#pragma unroll
  for (int r = 0; r < 4; ++r) {
    int row = q0 + wave * 16 + l4 * 4 + r;
    if (row < Sq) {
      float inv = 1.f / l_[r];
#pragma unroll
      for (int n = 0; n < 4; ++n)
        O[(size_t)(b * Sq + row) * 512 + hoff + n * 16 + l15] = f2bf(oacc[n][r] * inv);
    }
  }
}

// ---------------------------------------------------------------------------

extern "C" void kernel_launch(void* const* d_in, const int* in_sizes, int n_in,
                              void* d_out, int out_size, void* d_ws, size_t ws_size,
                              hipStream_t stream) {
  const float* src         = (const float*)d_in[0];
  const float* query_embed = (const float*)d_in[1];
  const float* pos_embed   = (const float*)d_in[2];
  const float* enc_attn_w  = (const float*)d_in[3];
  const float* enc_attn_b  = (const float*)d_in[4];
  const float* enc_w1      = (const float*)d_in[5];
  const float* enc_b1      = (const float*)d_in[6];
  const float* enc_w2      = (const float*)d_in[7];
  const float* enc_b2      = (const float*)d_in[8];
  const float* enc_ln_w    = (const float*)d_in[9];
  const float* enc_ln_b    = (const float*)d_in[10];
  const float* dec_sa_w    = (const float*)d_in[11];
  const float* dec_sa_b    = (const float*)d_in[12];
  const float* dec_ca_w    = (const float*)d_in[13];
  const float* dec_ca_b    = (const float*)d_in[14];
  const float* dec_w1      = (const float*)d_in[15];
  const float* dec_b1      = (const float*)d_in[16];
  const float* dec_w2      = (const float*)d_in[17];
  const float* dec_b2      = (const float*)d_in[18];
  const float* dec_ln_w    = (const float*)d_in[19];
  const float* dec_ln_b    = (const float*)d_in[20];
  float* out = (float*)d_out;

  const size_t ENC = 4UL * 1024 * 512;   // 2097152
  const size_t DEC = 4UL * 100 * 512;    // 204800
  const size_t MAT = 512UL * 512;        // 262144

  float* p = (float*)d_ws;
  float* x    = p; p += ENC;
  float* pos  = p; p += ENC;
  float* t1   = p; p += ENC;
  float* t2   = p; p += ENC;
  float* t3   = p; p += DEC;
  float* dstr = p; p += DEC;

  bfu* bp = (bfu*)p;
  bfu* t1b    = bp; bp += ENC;
  bfu* t2b    = bp; bp += ENC;
  bfu* t3b    = bp; bp += DEC;
  bfu* qkvb   = bp; bp += 4096UL * 1536;
  bfu* aob    = bp; bp += ENC;
  bfu* mob    = bp; bp += ENC;
  bfu* hbb    = bp; bp += 4096UL * 2048;
  bfu* meminb = bp; bp += ENC;
  bfu* ckvb   = bp; bp += 4096UL * 1024;
  // transposed bf16 weights
  bfu* enc_qkv_t = bp; bp += 18 * MAT;
  bfu* enc_out_t = bp; bp += 6 * MAT;
  bfu* enc_w1t   = bp; bp += 6UL * 512 * 2048;
  bfu* enc_w2t   = bp; bp += 6UL * 2048 * 512;
  bfu* dsa_qkv_t = bp; bp += 18 * MAT;
  bfu* dsa_out_t = bp; bp += 6 * MAT;
  bfu* dca_q_t   = bp; bp += 6 * MAT;
  bfu* dca_kv_t  = bp; bp += 12 * MAT;
  bfu* dca_out_t = bp; bp += 6 * MAT;
  bfu* dw1t      = bp; bp += 6UL * 512 * 2048;
  bfu* dw2t      = bp; bp += 6UL * 2048 * 512;

  dim3 tb(32, 8);
  k_transpose<<<dim3(16, 32, 4), tb, 0, stream>>>(src, x);
  k_transpose<<<dim3(16, 32, 4), tb, 0, stream>>>(pos_embed, pos);

  // weight conversion (once per launch)
  k_wt<<<dim3(16, 16, 18), tb, 0, stream>>>(enc_attn_w,            enc_qkv_t, 512, 512, 3, 4);
  k_wt<<<dim3(16, 16, 6),  tb, 0, stream>>>(enc_attn_w + 3 * MAT,  enc_out_t, 512, 512, 1, 4);
  k_wt<<<dim3(64, 16, 6),  tb, 0, stream>>>(enc_w1,                enc_w1t,   512, 2048, 1, 1);
  k_wt<<<dim3(16, 64, 6),  tb, 0, stream>>>(enc_w2,                enc_w2t,   2048, 512, 1, 1);
  k_wt<<<dim3(16, 16, 18), tb, 0, stream>>>(dec_sa_w,              dsa_qkv_t, 512, 512, 3, 4);
  k_wt<<<dim3(16, 16, 6),  tb, 0, stream>>>(dec_sa_w + 3 * MAT,    dsa_out_t, 512, 512, 1, 4);
  k_wt<<<dim3(16, 16, 6),  tb, 0, stream>>>(dec_ca_w,              dca_q_t,   512, 512, 1, 4);
  k_wt<<<dim3(16, 16, 12), tb, 0, stream>>>(dec_ca_w + 1 * MAT,    dca_kv_t,  512, 512, 2, 4);
  k_wt<<<dim3(16, 16, 6),  tb, 0, stream>>>(dec_ca_w + 3 * MAT,    dca_out_t, 512, 512, 1, 4);
  k_wt<<<dim3(64, 16, 6),  tb, 0, stream>>>(dec_w1,                dw1t,      512, 2048, 1, 1);
  k_wt<<<dim3(16, 64, 6),  tb, 0, stream>>>(dec_w2,                dw2t,      2048, 512, 1, 1);

  // ----------------------------- encoder ----------------------------------
  for (int l = 0; l < 6; ++l) {
    const float* ab = enc_attn_b + (size_t)l * 2048;
    k_add_dual<<<2048, 256, 0, stream>>>(x, pos, t1, t1b, (int)(ENC / 4));
    k_gemm_bf<<<dim3(12, 32), 256, 0, stream>>>(t1b, enc_qkv_t + (size_t)l * 3 * MAT, ab,
                                                qkvb, 4096, 1536, 512, 0);
    k_attn_mfma<<<dim3(16, 8, 4), 256, 0, stream>>>(qkvb, 1536, qkvb + 512, qkvb + 1024, 1536,
                                                    aob, 1024, 1024);
    k_gemm_bf<<<dim3(4, 32), 256, 0, stream>>>(aob, enc_out_t + (size_t)l * MAT, ab + 1536,
                                               mob, 4096, 512, 512, 0);
    k_ln<<<1024, 256, 0, stream>>>(t1, mob, enc_ln_w + (size_t)(l * 2 + 0) * 512,
                                   enc_ln_b + (size_t)(l * 2 + 0) * 512, t2, t2b, 4096);
    k_gemm_bf<<<dim3(16, 32), 256, 0, stream>>>(t2b, enc_w1t + (size_t)l * 512 * 2048,
                                                enc_b1 + (size_t)l * 2048, hbb,
                                                4096, 2048, 512, 1);
    k_gemm_bf<<<dim3(4, 32), 256, 0, stream>>>(hbb, enc_w2t + (size_t)l * 2048 * 512,
                                               enc_b2 + (size_t)l * 512, mob,
                                               4096, 512, 2048, 0);
    k_ln<<<1024, 256, 0, stream>>>(t2, mob, enc_ln_w + (size_t)(l * 2 + 1) * 512,
                                   enc_ln_b + (size_t)(l * 2 + 1) * 512, x, (bfu*)nullptr, 4096);
  }

  k_add_dual<<<2048, 256, 0, stream>>>(x, pos, (float*)nullptr, meminb, (int)(ENC / 4));
  k_zero<<<200, 256, 0, stream>>>(dstr, (int)(DEC / 4));

  // ----------------------------- decoder ----------------------------------
  for (int l = 0; l < 6; ++l) {
    const float* sb = dec_sa_b + (size_t)l * 2048;
    const float* cb = dec_ca_b + (size_t)l * 2048;
    k_add_qe_dual<<<200, 256, 0, stream>>>(dstr, query_embed, t1, t1b);
    // self-attention
    k_gemm_bf<<<dim3(12, 4), 256, 0, stream>>>(t1b, dsa_qkv_t + (size_t)l * 3 * MAT, sb,
                                               qkvb, 400, 1536, 512, 0);
    k_attn_mfma<<<dim3(2, 8, 4), 256, 0, stream>>>(qkvb, 1536, qkvb + 512, qkvb + 1024, 1536,
                                                   aob, 100, 100);
    k_gemm_bf<<<dim3(4, 4), 256, 0, stream>>>(aob, dsa_out_t + (size_t)l * MAT, sb + 1536,
                                              mob, 400, 512, 512, 0);
    k_ln<<<100, 256, 0, stream>>>(t1, mob, dec_ln_w + (size_t)(l * 3 + 0) * 512,
                                  dec_ln_b + (size_t)(l * 3 + 0) * 512, t2, t2b, 400);
    // cross-attention
    k_gemm_bf<<<dim3(4, 4), 256, 0, stream>>>(t2b, dca_q_t + (size_t)l * MAT, cb,
                                              qkvb, 400, 512, 512, 0);
    k_gemm_bf<<<dim3(8, 32), 256, 0, stream>>>(meminb, dca_kv_t + (size_t)l * 2 * MAT, cb + 512,
                                               ckvb, 4096, 1024, 512, 0);
    k_attn_mfma<<<dim3(2, 8, 4), 256, 0, stream>>>(qkvb, 512, ckvb, ckvb + 512, 1024,
                                                   aob, 100, 1024);
    k_gemm_bf<<<dim3(4, 4), 256, 0, stream>>>(aob, dca_out_t + (size_t)l * MAT, cb + 1536,
                                              mob, 400, 512, 512, 0);
    k_ln<<<100, 256, 0, stream>>>(t2, mob, dec_ln_w + (size_t)(l * 3 + 1) * 512,
                                  dec_ln_b + (size_t)(l * 3 + 1) * 512, t3, t3b, 400);
    // ffn
    k_gemm_bf<<<dim3(16, 4), 256, 0, stream>>>(t3b, dw1t + (size_t)l * 512 * 2048,
                                               dec_b1 + (size_t)l * 2048, hbb,
                                               400, 2048, 512, 1);
    k_gemm_bf<<<dim3(4, 4), 256, 0, stream>>>(hbb, dw2t + (size_t)l * 2048 * 512,
                                              dec_b2 + (size_t)l * 512, mob,
                                              400, 512, 2048, 0);
    k_ln<<<100, 256, 0, stream>>>(t3, mob, dec_ln_w + (size_t)(l * 3 + 2) * 512,
                                  dec_ln_b + (size_t)(l * 3 + 2) * 512, dstr, (bfu*)nullptr, 400);
  }

  k_copy<<<200, 256, 0, stream>>>(dstr, out, (int)(DEC / 4));
  k_copy<<<2048, 256, 0, stream>>>(x, out + DEC, (int)(ENC / 4));
}

// Round 4
// 2770.534 us; speedup vs baseline: 6.4063x; 1.1040x over previous
//
#include <hip/hip_runtime.h>
#include <math.h>

// ---------------------------------------------------------------------------
// DETR-style transformer. bf16 MFMA GEMMs (reg-prefetch, split-K) +
// bf16 MFMA flash attention. B=4, S=1024, NQ=100, D=512, H=8, FF=2048, L=6
// ---------------------------------------------------------------------------

typedef unsigned short bfu;
typedef unsigned int u32;
typedef __bf16 bf8v __attribute__((ext_vector_type(8)));
typedef float f32x4 __attribute__((ext_vector_type(4)));

__device__ inline bfu f2bf(float f) {
  union { float f; u32 u; } v; v.f = f;
  u32 u = v.u;
  u32 r = (u + 0x7fffu + ((u >> 16) & 1u)) >> 16;
  return (bfu)r;
}
__device__ inline float bflo(u32 u) { return __uint_as_float(u << 16); }

// ---------------- transpose f32 [B][C][S] -> [B][S][C] ----------------------
__global__ __launch_bounds__(256) void k_transpose(const float* __restrict__ in,
                                                   float* __restrict__ out) {
  __shared__ float tile[32][33];
  int b = blockIdx.z;
  int c0 = blockIdx.x * 32, s0 = blockIdx.y * 32;
  int tx = threadIdx.x, ty = threadIdx.y;  // (32, 8)
  for (int i = ty; i < 32; i += 8)
    tile[i][tx] = in[((size_t)(b * 512 + c0 + i)) * 1024 + s0 + tx];
  __syncthreads();
  for (int i = ty; i < 32; i += 8)
    out[((size_t)(b * 1024 + s0 + i)) * 512 + c0 + tx] = tile[tx][i];
}

// ---------------- weight transpose+convert: src f32 [K][N] -> dst bf16 [N][K]
__global__ __launch_bounds__(256) void k_wt(const float* __restrict__ src,
                                            bfu* __restrict__ dst,
                                            int K, int N, int nj, int lstride) {
  __shared__ bfu tile[32][33];
  int g = blockIdx.z;
  int l = g / nj, j = g - l * nj;
  const float* s = src + ((size_t)l * lstride + j) * (size_t)K * N;
  bfu* d = dst + (size_t)g * (size_t)K * N;
  int n0 = blockIdx.x * 32, k0 = blockIdx.y * 32;
  int tx = threadIdx.x, ty = threadIdx.y;  // (32, 8)
  for (int i = ty; i < 32; i += 8)
    tile[i][tx] = f2bf(s[(size_t)(k0 + i) * N + n0 + tx]);
  __syncthreads();
  for (int i = ty; i < 32; i += 8)
    d[(size_t)(n0 + i) * K + k0 + tx] = tile[tx][i];
}

// ---------------- elementwise adds -----------------------------------------
__global__ void k_add_dual(const float* __restrict__ a, const float* __restrict__ b,
                           float* __restrict__ of, bfu* __restrict__ ob, int n4) {
  int i = blockIdx.x * blockDim.x + threadIdx.x;
  if (i >= n4) return;
  float4 x = ((const float4*)a)[i];
  float4 y = ((const float4*)b)[i];
  float4 r = make_float4(x.x + y.x, x.y + y.y, x.z + y.z, x.w + y.w);
  if (of) ((float4*)of)[i] = r;
  if (ob) ((ushort4*)ob)[i] = make_ushort4(f2bf(r.x), f2bf(r.y), f2bf(r.z), f2bf(r.w));
}

__global__ void k_add_qe_dual(const float* __restrict__ a, const float* __restrict__ qe,
                              float* __restrict__ of, bfu* __restrict__ ob) {
  int i = blockIdx.x * blockDim.x + threadIdx.x;
  if (i >= 51200) return;
  int row = i >> 7;
  int q = row % 100;
  int c4 = i & 127;
  float4 x = ((const float4*)a)[i];
  float4 y = ((const float4*)qe)[q * 128 + c4];
  float4 r = make_float4(x.x + y.x, x.y + y.y, x.z + y.z, x.w + y.w);
  if (of) ((float4*)of)[i] = r;
  if (ob) ((ushort4*)ob)[i] = make_ushort4(f2bf(r.x), f2bf(r.y), f2bf(r.z), f2bf(r.w));
}

__global__ void k_zero(float* __restrict__ o, int n4) {
  int i = blockIdx.x * blockDim.x + threadIdx.x;
  if (i < n4) ((float4*)o)[i] = make_float4(0.f, 0.f, 0.f, 0.f);
}

// ---------------- LN(a + bf16 b) (decoder small path) -----------------------
__global__ __launch_bounds__(256) void k_ln(const float* __restrict__ A,
                                            const bfu* __restrict__ Bb,
                                            const float* __restrict__ g,
                                            const float* __restrict__ be,
                                            float* __restrict__ of,
                                            bfu* __restrict__ ob, int rows) {
  int row = blockIdx.x * 4 + (threadIdx.x >> 6);
  int lane = threadIdx.x & 63;
  if (row >= rows) return;
  const float* pa = A + (size_t)row * 512;
  const bfu* pb = Bb + (size_t)row * 512;
  float v[8];
  float s = 0.f, s2 = 0.f;
#pragma unroll
  for (int j = 0; j < 8; ++j) {
    int c = lane + j * 64;
    float x = pa[c] + bflo((u32)pb[c]);
    v[j] = x; s += x; s2 += x * x;
  }
#pragma unroll
  for (int off = 32; off > 0; off >>= 1) {
    s += __shfl_xor(s, off);
    s2 += __shfl_xor(s2, off);
  }
  float mean = s * (1.f / 512.f);
  float var = s2 * (1.f / 512.f) - mean * mean;
  float r = rsqrtf(var + 1e-5f);
#pragma unroll
  for (int j = 0; j < 8; ++j) {
    int c = lane + j * 64;
    float o = (v[j] - mean) * r * g[c] + be[c];
    of[(size_t)row * 512 + c] = o;
    if (ob) ob[(size_t)row * 512 + c] = f2bf(o);
  }
}

// ---------------- LN(a + sum_z P[z] + bias) — split-K reduce fused ---------
__global__ __launch_bounds__(256) void k_ln_red(const float* __restrict__ A,
                                                const float* __restrict__ P,
                                                int nsplit, size_t pz,
                                                const float* __restrict__ bias,
                                                const float* __restrict__ g,
                                                const float* __restrict__ be,
                                                float* __restrict__ of,
                                                bfu* __restrict__ ob, int rows) {
  int row = blockIdx.x * 4 + (threadIdx.x >> 6);
  int lane = threadIdx.x & 63;
  if (row >= rows) return;
  const float* pa = A + (size_t)row * 512;
  float v[8];
  float s = 0.f, s2 = 0.f;
#pragma unroll
  for (int j = 0; j < 8; ++j) {
    int c = lane + j * 64;
    float x = pa[c] + bias[c];
    for (int z = 0; z < nsplit; ++z) x += P[z * pz + (size_t)row * 512 + c];
    v[j] = x; s += x; s2 += x * x;
  }
#pragma unroll
  for (int off = 32; off > 0; off >>= 1) {
    s += __shfl_xor(s, off);
    s2 += __shfl_xor(s2, off);
  }
  float mean = s * (1.f / 512.f);
  float var = s2 * (1.f / 512.f) - mean * mean;
  float r = rsqrtf(var + 1e-5f);
#pragma unroll
  for (int j = 0; j < 8; ++j) {
    int c = lane + j * 64;
    float o = (v[j] - mean) * r * g[c] + be[c];
    of[(size_t)row * 512 + c] = o;
    if (ob) ob[(size_t)row * 512 + c] = f2bf(o);
  }
}

// ---------------- bf16 MFMA GEMM, reg-prefetch, optional z-batch -----------
// C[M,N] = A[M,K] @ Wt[N,K]^T + bias; z-batched via strides.
__global__ __launch_bounds__(256) void k_gemm_bf(const bfu* __restrict__ A,
                                                 const bfu* __restrict__ Wt,
                                                 const float* __restrict__ bias,
                                                 bfu* __restrict__ C,
                                                 int M, int N, int K, int relu,
                                                 size_t wtz, size_t cz, int bz) {
  __shared__ bfu As[128][72];
  __shared__ bfu Bs[128][72];
  int z = blockIdx.z;
  Wt += (size_t)z * wtz; C += (size_t)z * cz; bias += z * bz;
  int bm = blockIdx.y * 128, bn = blockIdx.x * 128;
  int t = threadIdx.x;
  int wave = t >> 6, lane = t & 63;
  int wm = wave >> 1, wn = wave & 1;
  int l15 = lane & 15, l4 = lane >> 4;
  f32x4 acc[4][4];
  f32x4 zz = {0.f, 0.f, 0.f, 0.f};
#pragma unroll
  for (int mi = 0; mi < 4; ++mi)
#pragma unroll
    for (int ni = 0; ni < 4; ++ni) acc[mi][ni] = zz;

  uint4 ra[4], rb[4];
  const uint4 uz = {0u, 0u, 0u, 0u};
  auto load = [&](int k0) {
#pragma unroll
    for (int i = 0; i < 4; ++i) {
      int c = t + i * 256;
      int row = c >> 3, kg = c & 7;
      ra[i] = uz;
      if (bm + row < M) ra[i] = *(const uint4*)(A + (size_t)(bm + row) * K + k0 + kg * 8);
      rb[i] = *(const uint4*)(Wt + (size_t)(bn + row) * K + k0 + kg * 8);
    }
  };
  load(0);
  for (int k0 = 0; k0 < K; k0 += 64) {
#pragma unroll
    for (int i = 0; i < 4; ++i) {
      int c = t + i * 256;
      int row = c >> 3, kg = c & 7;
      *(uint4*)&As[row][kg * 8] = ra[i];
      *(uint4*)&Bs[row][kg * 8] = rb[i];
    }
    __syncthreads();
    if (k0 + 64 < K) load(k0 + 64);   // prefetch next tile; drained at barrier
#pragma unroll
    for (int kc = 0; kc < 2; ++kc) {
      bf8v av[4], bv[4];
#pragma unroll
      for (int mi = 0; mi < 4; ++mi)
        av[mi] = *(const bf8v*)&As[wm * 64 + mi * 16 + l15][kc * 32 + l4 * 8];
#pragma unroll
      for (int ni = 0; ni < 4; ++ni)
        bv[ni] = *(const bf8v*)&Bs[wn * 64 + ni * 16 + l15][kc * 32 + l4 * 8];
#pragma unroll
      for (int mi = 0; mi < 4; ++mi)
#pragma unroll
        for (int ni = 0; ni < 4; ++ni)
          acc[mi][ni] = __builtin_amdgcn_mfma_f32_16x16x32_bf16(av[mi], bv[ni],
                                                                acc[mi][ni], 0, 0, 0);
    }
    __syncthreads();
  }

#pragma unroll
  for (int mi = 0; mi < 4; ++mi) {
    int row0 = bm + wm * 64 + mi * 16 + l4 * 4;
#pragma unroll
    for (int ni = 0; ni < 4; ++ni) {
      int col = bn + wn * 64 + ni * 16 + l15;
      float bb = bias[col];
#pragma unroll
      for (int r = 0; r < 4; ++r) {
        int row = row0 + r;
        if (row < M) {
          float v = acc[mi][ni][r] + bb;
          if (relu) v = fmaxf(v, 0.f);
          C[(size_t)row * N + col] = f2bf(v);
        }
      }
    }
  }
}

// ---------------- split-K GEMM -> f32 partials (no bias/relu) --------------
__global__ __launch_bounds__(256) void k_gemm_sk(const bfu* __restrict__ A,
                                                 const bfu* __restrict__ Wt,
                                                 float* __restrict__ Pf,
                                                 int M, int N, int K, int ksplit) {
  __shared__ bfu As[128][72];
  __shared__ bfu Bs[128][72];
  int z = blockIdx.z;
  int Kc = K / ksplit;
  int kbeg = z * Kc;
  Pf += (size_t)z * M * N;
  int bm = blockIdx.y * 128, bn = blockIdx.x * 128;
  int t = threadIdx.x;
  int wave = t >> 6, lane = t & 63;
  int wm = wave >> 1, wn = wave & 1;
  int l15 = lane & 15, l4 = lane >> 4;
  f32x4 acc[4][4];
  f32x4 zz = {0.f, 0.f, 0.f, 0.f};
#pragma unroll
  for (int mi = 0; mi < 4; ++mi)
#pragma unroll
    for (int ni = 0; ni < 4; ++ni) acc[mi][ni] = zz;

  uint4 ra[4], rb[4];
  const uint4 uz = {0u, 0u, 0u, 0u};
  auto load = [&](int k0) {
#pragma unroll
    for (int i = 0; i < 4; ++i) {
      int c = t + i * 256;
      int row = c >> 3, kg = c & 7;
      ra[i] = uz;
      if (bm + row < M) ra[i] = *(const uint4*)(A + (size_t)(bm + row) * K + k0 + kg * 8);
      rb[i] = *(const uint4*)(Wt + (size_t)(bn + row) * K + k0 + kg * 8);
    }
  };
  load(kbeg);
  for (int k0 = kbeg; k0 < kbeg + Kc; k0 += 64) {
#pragma unroll
    for (int i = 0; i < 4; ++i) {
      int c = t + i * 256;
      int row = c >> 3, kg = c & 7;
      *(uint4*)&As[row][kg * 8] = ra[i];
      *(uint4*)&Bs[row][kg * 8] = rb[i];
    }
    __syncthreads();
    if (k0 + 64 < kbeg + Kc) load(k0 + 64);
#pragma unroll
    for (int kc = 0; kc < 2; ++kc) {
      bf8v av[4], bv[4];
#pragma unroll
      for (int mi = 0; mi < 4; ++mi)
        av[mi] = *(const bf8v*)&As[wm * 64 + mi * 16 + l15][kc * 32 + l4 * 8];
#pragma unroll
      for (int ni = 0; ni < 4; ++ni)
        bv[ni] = *(const bf8v*)&Bs[wn * 64 + ni * 16 + l15][kc * 32 + l4 * 8];
#pragma unroll
      for (int mi = 0; mi < 4; ++mi)
#pragma unroll
        for (int ni = 0; ni < 4; ++ni)
          acc[mi][ni] = __builtin_amdgcn_mfma_f32_16x16x32_bf16(av[mi], bv[ni],
                                                                acc[mi][ni], 0, 0, 0);
    }
    __syncthreads();
  }

#pragma unroll
  for (int mi = 0; mi < 4; ++mi) {
    int row0 = bm + wm * 64 + mi * 16 + l4 * 4;
#pragma unroll
    for (int ni = 0; ni < 4; ++ni) {
      int col = bn + wn * 64 + ni * 16 + l15;
#pragma unroll
      for (int r = 0; r < 4; ++r) {
        int row = row0 + r;
        if (row < M) Pf[(size_t)row * N + col] = acc[mi][ni][r];
      }
    }
  }
}

// ---------------- MFMA flash attention with KV reg-prefetch ----------------
__global__ __launch_bounds__(256) void k_attn_mfma(const bfu* __restrict__ Q, int qs,
                                                   const bfu* __restrict__ Km,
                                                   const bfu* __restrict__ Vm, int kvs,
                                                   bfu* __restrict__ O,
                                                   int Sq, int Sk) {
  __shared__ bfu Ks[64][72];
  __shared__ bfu Vt[64][72];       // Vt[d][kv]
  __shared__ bfu Sm[4][16][72];    // per-wave P tile
  const float scale = 0.125f;
  int b = blockIdx.z, h = blockIdx.y;
  int q0 = blockIdx.x * 64;
  int t = threadIdx.x;
  int wave = t >> 6, lane = t & 63;
  int l15 = lane & 15, l4 = lane >> 4;
  int hoff = h * 64;

  uint4 uq0 = {0u, 0u, 0u, 0u}, uq1 = {0u, 0u, 0u, 0u};
  {
    int qrow = q0 + wave * 16 + l15;
    if (qrow < Sq) {
      const bfu* qp = Q + (size_t)(b * Sq + qrow) * qs + hoff + l4 * 8;
      uq0 = *(const uint4*)qp;
      uq1 = *(const uint4*)(qp + 32);
    }
  }
  bf8v qf0 = *(bf8v*)&uq0, qf1 = *(bf8v*)&uq1;

  float m_[4] = {-1e30f, -1e30f, -1e30f, -1e30f};
  float l_[4] = {0.f, 0.f, 0.f, 0.f};
  f32x4 oacc[4];
  f32x4 zz = {0.f, 0.f, 0.f, 0.f};
#pragma unroll
  for (int n = 0; n < 4; ++n) oacc[n] = zz;

  uint4 ruk[2], ruv[2];
  const uint4 uz = {0u, 0u, 0u, 0u};
  auto load_kv = [&](int k0) {
#pragma unroll
    for (int i = 0; i < 2; ++i) {
      int e = t + i * 256;
      int rk = e >> 3, cg = e & 7;
      ruk[i] = uz;
      if (k0 + rk < Sk)
        ruk[i] = *(const uint4*)(Km + (size_t)(b * Sk + k0 + rk) * kvs + hoff + cg * 8);
      int kv = e & 63, dg = e >> 6;
      ruv[i] = uz;
      if (k0 + kv < Sk)
        ruv[i] = *(const uint4*)(Vm + (size_t)(b * Sk + k0 + kv) * kvs + hoff + dg * 8);
    }
  };
  load_kv(0);

  for (int k0 = 0; k0 < Sk; k0 += 64) {
#pragma unroll
    for (int i = 0; i < 2; ++i) {
      int e = t + i * 256;
      int rk = e >> 3, cg = e & 7;
      *(uint4*)&Ks[rk][cg * 8] = ruk[i];
      int kv = e & 63, dg = e >> 6;
      bfu vv[8];
      *(uint4*)vv = ruv[i];
#pragma unroll
      for (int j = 0; j < 8; ++j) Vt[dg * 8 + j][kv] = vv[j];
    }
    __syncthreads();  // (1) tiles ready
    if (k0 + 64 < Sk) load_kv(k0 + 64);   // prefetch next chunk

    f32x4 s4[4];
#pragma unroll
    for (int tt = 0; tt < 4; ++tt) {
      bf8v kf0 = *(const bf8v*)&Ks[tt * 16 + l15][l4 * 8];
      bf8v kf1 = *(const bf8v*)&Ks[tt * 16 + l15][32 + l4 * 8];
      f32x4 a = zz;
      a = __builtin_amdgcn_mfma_f32_16x16x32_bf16(qf0, kf0, a, 0, 0, 0);
      a = __builtin_amdgcn_mfma_f32_16x16x32_bf16(qf1, kf1, a, 0, 0, 0);
      s4[tt] = a;
    }

    float f_[4];
#pragma unroll
    for (int r = 0; r < 4; ++r) {
      float sv[4];
      float mx = -1e30f;
#pragma unroll
      for (int tt = 0; tt < 4; ++tt) {
        float s = s4[tt][r] * scale;
        s = (k0 + tt * 16 + l15 < Sk) ? s : -1e30f;
        sv[tt] = s;
        mx = fmaxf(mx, s);
      }
#pragma unroll
      for (int off = 1; off < 16; off <<= 1) mx = fmaxf(mx, __shfl_xor(mx, off));
      float nm = fmaxf(m_[r], mx);
      float f = __expf(m_[r] - nm);
      float ps = 0.f;
#pragma unroll
      for (int tt = 0; tt < 4; ++tt) {
        float p = __expf(sv[tt] - nm);
        ps += p;
        Sm[wave][l4 * 4 + r][tt * 16 + l15] = f2bf(p);
      }
#pragma unroll
      for (int off = 1; off < 16; off <<= 1) ps += __shfl_xor(ps, off);
      l_[r] = l_[r] * f + ps;
      m_[r] = nm;
      f_[r] = f;
    }
#pragma unroll
    for (int n = 0; n < 4; ++n)
#pragma unroll
      for (int r = 0; r < 4; ++r) oacc[n][r] *= f_[r];

    bf8v p0 = *(const bf8v*)&Sm[wave][l15][l4 * 8];
    bf8v p1 = *(const bf8v*)&Sm[wave][l15][32 + l4 * 8];
#pragma unroll
    for (int n = 0; n < 4; ++n) {
      bf8v v0 = *(const bf8v*)&Vt[n * 16 + l15][l4 * 8];
      bf8v v1 = *(const bf8v*)&Vt[n * 16 + l15][32 + l4 * 8];
      oacc[n] = __builtin_amdgcn_mfma_f32_16x16x32_bf16(p0, v0, oacc[n], 0, 0, 0);
      oacc[n] = __builtin_amdgcn_mfma_f32_16x16x32_bf16(p1, v1, oacc[n], 0, 0, 0);
    }
    __syncthreads();  // (2) done reading tiles
  }

#pragma unroll
  for (int r = 0; r < 4; ++r) {
    int row = q0 + wave * 16 + l4 * 4 + r;
    if (row < Sq) {
      float inv = 1.f / l_[r];
#pragma unroll
      for (int n = 0; n < 4; ++n)
        O[(size_t)(b * Sq + row) * 512 + hoff + n * 16 + l15] = f2bf(oacc[n][r] * inv);
    }
  }
}

// ---------------------------------------------------------------------------

extern "C" void kernel_launch(void* const* d_in, const int* in_sizes, int n_in,
                              void* d_out, int out_size, void* d_ws, size_t ws_size,
                              hipStream_t stream) {
  const float* src         = (const float*)d_in[0];
  const float* query_embed = (const float*)d_in[1];
  const float* pos_embed   = (const float*)d_in[2];
  const float* enc_attn_w  = (const float*)d_in[3];
  const float* enc_attn_b  = (const float*)d_in[4];
  const float* enc_w1      = (const float*)d_in[5];
  const float* enc_b1      = (const float*)d_in[6];
  const float* enc_w2      = (const float*)d_in[7];
  const float* enc_b2      = (const float*)d_in[8];
  const float* enc_ln_w    = (const float*)d_in[9];
  const float* enc_ln_b    = (const float*)d_in[10];
  const float* dec_sa_w    = (const float*)d_in[11];
  const float* dec_sa_b    = (const float*)d_in[12];
  const float* dec_ca_w    = (const float*)d_in[13];
  const float* dec_ca_b    = (const float*)d_in[14];
  const float* dec_w1      = (const float*)d_in[15];
  const float* dec_b1      = (const float*)d_in[16];
  const float* dec_w2      = (const float*)d_in[17];
  const float* dec_b2      = (const float*)d_in[18];
  const float* dec_ln_w    = (const float*)d_in[19];
  const float* dec_ln_b    = (const float*)d_in[20];
  float* out = (float*)d_out;

  const size_t ENC = 4UL * 1024 * 512;   // 2097152
  const size_t DEC = 4UL * 100 * 512;    // 204800
  const size_t MAT = 512UL * 512;        // 262144

  float* p = (float*)d_ws;
  float* x    = p; p += ENC;
  float* pos  = p; p += ENC;
  float* t1   = p; p += ENC;
  float* t2   = p; p += ENC;
  float* t3   = p; p += DEC;
  float* dstr = p; p += DEC;
  float* Pf   = p; p += 4 * ENC;   // split-K f32 partials (max 4 x 4096 x 512)

  bfu* bp = (bfu*)p;
  bfu* t1b    = bp; bp += ENC;
  bfu* t2b    = bp; bp += ENC;
  bfu* t3b    = bp; bp += DEC;
  bfu* qkvb   = bp; bp += 4096UL * 1536;
  bfu* aob    = bp; bp += ENC;
  bfu* mob    = bp; bp += ENC;
  bfu* hbb    = bp; bp += 4096UL * 2048;
  bfu* meminb = bp; bp += ENC;
  bfu* ckvb   = bp; bp += 6UL * 4096 * 1024;  // 6 layers of batched CA K/V
  // transposed bf16 weights
  bfu* enc_qkv_t = bp; bp += 18 * MAT;
  bfu* enc_out_t = bp; bp += 6 * MAT;
  bfu* enc_w1t   = bp; bp += 6UL * 512 * 2048;
  bfu* enc_w2t   = bp; bp += 6UL * 2048 * 512;
  bfu* dsa_qkv_t = bp; bp += 18 * MAT;
  bfu* dsa_out_t = bp; bp += 6 * MAT;
  bfu* dca_q_t   = bp; bp += 6 * MAT;
  bfu* dca_kv_t  = bp; bp += 12 * MAT;
  bfu* dca_out_t = bp; bp += 6 * MAT;
  bfu* dw1t      = bp; bp += 6UL * 512 * 2048;
  bfu* dw2t      = bp; bp += 6UL * 2048 * 512;

  dim3 tb(32, 8);
  k_transpose<<<dim3(16, 32, 4), tb, 0, stream>>>(src, x);
  k_transpose<<<dim3(16, 32, 4), tb, 0, stream>>>(pos_embed, pos);

  // weight conversion (once per launch)
  k_wt<<<dim3(16, 16, 18), tb, 0, stream>>>(enc_attn_w,            enc_qkv_t, 512, 512, 3, 4);
  k_wt<<<dim3(16, 16, 6),  tb, 0, stream>>>(enc_attn_w + 3 * MAT,  enc_out_t, 512, 512, 1, 4);
  k_wt<<<dim3(64, 16, 6),  tb, 0, stream>>>(enc_w1,                enc_w1t,   512, 2048, 1, 1);
  k_wt<<<dim3(16, 64, 6),  tb, 0, stream>>>(enc_w2,                enc_w2t,   2048, 512, 1, 1);
  k_wt<<<dim3(16, 16, 18), tb, 0, stream>>>(dec_sa_w,              dsa_qkv_t, 512, 512, 3, 4);
  k_wt<<<dim3(16, 16, 6),  tb, 0, stream>>>(dec_sa_w + 3 * MAT,    dsa_out_t, 512, 512, 1, 4);
  k_wt<<<dim3(16, 16, 6),  tb, 0, stream>>>(dec_ca_w,              dca_q_t,   512, 512, 1, 4);
  k_wt<<<dim3(16, 16, 12), tb, 0, stream>>>(dec_ca_w + 1 * MAT,    dca_kv_t,  512, 512, 2, 4);
  k_wt<<<dim3(16, 16, 6),  tb, 0, stream>>>(dec_ca_w + 3 * MAT,    dca_out_t, 512, 512, 1, 4);
  k_wt<<<dim3(64, 16, 6),  tb, 0, stream>>>(dec_w1,                dw1t,      512, 2048, 1, 1);
  k_wt<<<dim3(16, 64, 6),  tb, 0, stream>>>(dec_w2,                dw2t,      2048, 512, 1, 1);

  // ----------------------------- encoder ----------------------------------
  for (int l = 0; l < 6; ++l) {
    const float* ab = enc_attn_b + (size_t)l * 2048;
    float* xout = (l == 5) ? (out + DEC) : x;   // final layer writes memory output
    k_add_dual<<<2048, 256, 0, stream>>>(x, pos, t1, t1b, (int)(ENC / 4));
    k_gemm_bf<<<dim3(12, 32), 256, 0, stream>>>(t1b, enc_qkv_t + (size_t)l * 3 * MAT, ab,
                                                qkvb, 4096, 1536, 512, 0, 0, 0, 0);
    k_attn_mfma<<<dim3(16, 8, 4), 256, 0, stream>>>(qkvb, 1536, qkvb + 512, qkvb + 1024, 1536,
                                                    aob, 1024, 1024);
    k_gemm_sk<<<dim3(4, 32, 2), 256, 0, stream>>>(aob, enc_out_t + (size_t)l * MAT, Pf,
                                                  4096, 512, 512, 2);
    k_ln_red<<<1024, 256, 0, stream>>>(t1, Pf, 2, ENC, ab + 1536,
                                       enc_ln_w + (size_t)(l * 2 + 0) * 512,
                                       enc_ln_b + (size_t)(l * 2 + 0) * 512, t2, t2b, 4096);
    k_gemm_bf<<<dim3(16, 32), 256, 0, stream>>>(t2b, enc_w1t + (size_t)l * 512 * 2048,
                                                enc_b1 + (size_t)l * 2048, hbb,
                                                4096, 2048, 512, 1, 0, 0, 0);
    k_gemm_sk<<<dim3(4, 32, 4), 256, 0, stream>>>(hbb, enc_w2t + (size_t)l * 2048 * 512, Pf,
                                                  4096, 512, 2048, 4);
    k_ln_red<<<1024, 256, 0, stream>>>(t2, Pf, 4, ENC, enc_b2 + (size_t)l * 512,
                                       enc_ln_w + (size_t)(l * 2 + 1) * 512,
                                       enc_ln_b + (size_t)(l * 2 + 1) * 512,
                                       xout, (bfu*)nullptr, 4096);
  }

  k_add_dual<<<2048, 256, 0, stream>>>(out + DEC, pos, (float*)nullptr, meminb, (int)(ENC / 4));
  k_zero<<<200, 256, 0, stream>>>(dstr, (int)(DEC / 4));

  // all 6 decoder layers' cross-attn K/V projections in one dispatch
  k_gemm_bf<<<dim3(8, 32, 6), 256, 0, stream>>>(meminb, dca_kv_t, dec_ca_b + 512,
                                                ckvb, 4096, 1024, 512, 0,
                                                2 * MAT, 4096UL * 1024, 2048);

  // ----------------------------- decoder ----------------------------------
  for (int l = 0; l < 6; ++l) {
    const float* sb = dec_sa_b + (size_t)l * 2048;
    const float* cb = dec_ca_b + (size_t)l * 2048;
    float* dout = (l == 5) ? out : dstr;
    k_add_qe_dual<<<200, 256, 0, stream>>>(dstr, query_embed, t1, t1b);
    // self-attention
    k_gemm_bf<<<dim3(12, 4), 256, 0, stream>>>(t1b, dsa_qkv_t + (size_t)l * 3 * MAT, sb,
                                               qkvb, 400, 1536, 512, 0, 0, 0, 0);
    k_attn_mfma<<<dim3(2, 8, 4), 256, 0, stream>>>(qkvb, 1536, qkvb + 512, qkvb + 1024, 1536,
                                                   aob, 100, 100);
    k_gemm_sk<<<dim3(4, 4, 2), 256, 0, stream>>>(aob, dsa_out_t + (size_t)l * MAT, Pf,
                                                 400, 512, 512, 2);
    k_ln_red<<<100, 256, 0, stream>>>(t1, Pf, 2, 400UL * 512, sb + 1536,
                                      dec_ln_w + (size_t)(l * 3 + 0) * 512,
                                      dec_ln_b + (size_t)(l * 3 + 0) * 512, t2, t2b, 400);
    // cross-attention
    k_gemm_bf<<<dim3(4, 4), 256, 0, stream>>>(t2b, dca_q_t + (size_t)l * MAT, cb,
                                              qkvb, 400, 512, 512, 0, 0, 0, 0);
    k_attn_mfma<<<dim3(2, 8, 4), 256, 0, stream>>>(qkvb, 512,
                                                   ckvb + (size_t)l * 4096 * 1024,
                                                   ckvb + (size_t)l * 4096 * 1024 + 512, 1024,
                                                   aob, 100, 1024);
    k_gemm_sk<<<dim3(4, 4, 2), 256, 0, stream>>>(aob, dca_out_t + (size_t)l * MAT, Pf,
                                                 400, 512, 512, 2);
    k_ln_red<<<100, 256, 0, stream>>>(t2, Pf, 2, 400UL * 512, cb + 1536,
                                      dec_ln_w + (size_t)(l * 3 + 1) * 512,
                                      dec_ln_b + (size_t)(l * 3 + 1) * 512, t3, t3b, 400);
    // ffn
    k_gemm_bf<<<dim3(16, 4), 256, 0, stream>>>(t3b, dw1t + (size_t)l * 512 * 2048,
                                               dec_b1 + (size_t)l * 2048, hbb,
                                               400, 2048, 512, 1, 0, 0, 0);
    k_gemm_sk<<<dim3(4, 4, 4), 256, 0, stream>>>(hbb, dw2t + (size_t)l * 2048 * 512, Pf,
                                                 400, 512, 2048, 4);
    k_ln_red<<<100, 256, 0, stream>>>(t3, Pf, 4, 400UL * 512, dec_b2 + (size_t)l * 512,
                                      dec_ln_w + (size_t)(l * 3 + 2) * 512,
                                      dec_ln_b + (size_t)(l * 3 + 2) * 512,
                                      dout, (bfu*)nullptr, 400);
  }
}

// Round 5
// 2033.906 us; speedup vs baseline: 8.7266x; 1.3622x over previous
//
#include <hip/hip_runtime.h>
#include <math.h>

// ---------------------------------------------------------------------------
// DETR-style transformer. bf16 MFMA GEMMs (global_load_lds, 2-phase dbuf,
// XOR-swizzled LDS) + bf16 MFMA flash attention.
// B=4, S=1024, NQ=100, D=512, H=8, dk=64, FF=2048, L=6
// ---------------------------------------------------------------------------

typedef unsigned short bfu;
typedef unsigned int u32;
typedef __bf16 bf8v __attribute__((ext_vector_type(8)));
typedef float f32x4 __attribute__((ext_vector_type(4)));

__device__ inline bfu f2bf(float f) {
  union { float f; u32 u; } v; v.f = f;
  u32 u = v.u;
  u32 r = (u + 0x7fffu + ((u >> 16) & 1u)) >> 16;
  return (bfu)r;
}
__device__ inline float bflo(u32 u) { return __uint_as_float(u << 16); }

// async global->LDS, 16 bytes per lane (wave-uniform LDS base + lane*16)
typedef const __attribute__((address_space(1))) u32 gas_t;
typedef __attribute__((address_space(3))) u32 las_t;
__device__ __forceinline__ void gl16(const void* g, void* l) {
  __builtin_amdgcn_global_load_lds((gas_t*)g, (las_t*)l, 16, 0, 0);
}

// ---------------- transpose f32 [B][C][S] -> [B][S][C] ----------------------
__global__ __launch_bounds__(256) void k_transpose(const float* __restrict__ in,
                                                   float* __restrict__ out) {
  __shared__ float tile[32][33];
  int b = blockIdx.z;
  int c0 = blockIdx.x * 32, s0 = blockIdx.y * 32;
  int tx = threadIdx.x, ty = threadIdx.y;  // (32, 8)
  for (int i = ty; i < 32; i += 8)
    tile[i][tx] = in[((size_t)(b * 512 + c0 + i)) * 1024 + s0 + tx];
  __syncthreads();
  for (int i = ty; i < 32; i += 8)
    out[((size_t)(b * 1024 + s0 + i)) * 512 + c0 + tx] = tile[tx][i];
}

// ---------------- weight transpose+convert: src f32 [K][N] -> dst bf16 [N][K]
__global__ __launch_bounds__(256) void k_wt(const float* __restrict__ src,
                                            bfu* __restrict__ dst,
                                            int K, int N, int nj, int lstride) {
  __shared__ bfu tile[32][33];
  int g = blockIdx.z;
  int l = g / nj, j = g - l * nj;
  const float* s = src + ((size_t)l * lstride + j) * (size_t)K * N;
  bfu* d = dst + (size_t)g * (size_t)K * N;
  int n0 = blockIdx.x * 32, k0 = blockIdx.y * 32;
  int tx = threadIdx.x, ty = threadIdx.y;  // (32, 8)
  for (int i = ty; i < 32; i += 8)
    tile[i][tx] = f2bf(s[(size_t)(k0 + i) * N + n0 + tx]);
  __syncthreads();
  for (int i = ty; i < 32; i += 8)
    d[(size_t)(n0 + i) * K + k0 + tx] = tile[tx][i];
}

// ---------------- elementwise adds -----------------------------------------
__global__ void k_add_dual(const float* __restrict__ a, const float* __restrict__ b,
                           float* __restrict__ of, bfu* __restrict__ ob, int n4) {
  int i = blockIdx.x * blockDim.x + threadIdx.x;
  if (i >= n4) return;
  float4 x = ((const float4*)a)[i];
  float4 y = ((const float4*)b)[i];
  float4 r = make_float4(x.x + y.x, x.y + y.y, x.z + y.z, x.w + y.w);
  if (of) ((float4*)of)[i] = r;
  if (ob) ((ushort4*)ob)[i] = make_ushort4(f2bf(r.x), f2bf(r.y), f2bf(r.z), f2bf(r.w));
}

__global__ void k_add_qe_dual(const float* __restrict__ a, const float* __restrict__ qe,
                              float* __restrict__ of, bfu* __restrict__ ob) {
  int i = blockIdx.x * blockDim.x + threadIdx.x;
  if (i >= 51200) return;
  int row = i >> 7;
  int q = row % 100;
  int c4 = i & 127;
  float4 x = ((const float4*)a)[i];
  float4 y = ((const float4*)qe)[q * 128 + c4];
  float4 r = make_float4(x.x + y.x, x.y + y.y, x.z + y.z, x.w + y.w);
  if (of) ((float4*)of)[i] = r;
  if (ob) ((ushort4*)ob)[i] = make_ushort4(f2bf(r.x), f2bf(r.y), f2bf(r.z), f2bf(r.w));
}

__global__ void k_zero(float* __restrict__ o, int n4) {
  int i = blockIdx.x * blockDim.x + threadIdx.x;
  if (i < n4) ((float4*)o)[i] = make_float4(0.f, 0.f, 0.f, 0.f);
}

// ---------------- LN(a + sum_z P[z] + bias) — split-K reduce fused ---------
__global__ __launch_bounds__(256) void k_ln_red(const float* __restrict__ A,
                                                const float* __restrict__ P,
                                                int nsplit, size_t pz,
                                                const float* __restrict__ bias,
                                                const float* __restrict__ g,
                                                const float* __restrict__ be,
                                                float* __restrict__ of,
                                                bfu* __restrict__ ob, int rows) {
  int row = blockIdx.x * 4 + (threadIdx.x >> 6);
  int lane = threadIdx.x & 63;
  if (row >= rows) return;
  const float* pa = A + (size_t)row * 512;
  float v[8];
  float s = 0.f, s2 = 0.f;
#pragma unroll
  for (int j = 0; j < 8; ++j) {
    int c = lane + j * 64;
    float x = pa[c] + bias[c];
    for (int z = 0; z < nsplit; ++z) x += P[z * pz + (size_t)row * 512 + c];
    v[j] = x; s += x; s2 += x * x;
  }
#pragma unroll
  for (int off = 32; off > 0; off >>= 1) {
    s += __shfl_xor(s, off);
    s2 += __shfl_xor(s2, off);
  }
  float mean = s * (1.f / 512.f);
  float var = s2 * (1.f / 512.f) - mean * mean;
  float r = rsqrtf(var + 1e-5f);
#pragma unroll
  for (int j = 0; j < 8; ++j) {
    int c = lane + j * 64;
    float o = (v[j] - mean) * r * g[c] + be[c];
    of[(size_t)row * 512 + c] = o;
    if (ob) ob[(size_t)row * 512 + c] = f2bf(o);
  }
}

// ---------------- bf16 MFMA GEMM: global_load_lds + 2-phase double buffer --
// C[M,N] = A[M,K] @ Wt[N,K]^T + bias; z-batched via strides.
// LDS linear [128][64] per tile; chunk swizzle kg^(row&7) applied on BOTH the
// global source address and the ds_read address (involution).
__global__ __launch_bounds__(256) void k_gemm_bf(const bfu* __restrict__ A,
                                                 const bfu* __restrict__ Wt,
                                                 const float* __restrict__ bias,
                                                 bfu* __restrict__ C,
                                                 int M, int N, int K, int relu,
                                                 size_t wtz, size_t cz, int bz) {
  __shared__ bfu As[2][128][64];
  __shared__ bfu Bs[2][128][64];
  int z = blockIdx.z;
  Wt += (size_t)z * wtz; C += (size_t)z * cz; bias += z * bz;
  int bm = blockIdx.y * 128, bn = blockIdx.x * 128;
  int t = threadIdx.x;
  int wave = t >> 6, lane = t & 63;
  int wm = wave >> 1, wn = wave & 1;
  int l15 = lane & 15, l4 = lane >> 4;
  f32x4 acc[4][4];
  f32x4 zz = {0.f, 0.f, 0.f, 0.f};
#pragma unroll
  for (int mi = 0; mi < 4; ++mi)
#pragma unroll
    for (int ni = 0; ni < 4; ++ni) acc[mi][ni] = zz;

  auto stage = [&](int buf, int k0) {
#pragma unroll
    for (int i = 0; i < 4; ++i) {
      int c = t + i * 256;            // 0..1023 chunks of 16B
      int row = c >> 3, kg = c & 7;
      int sc = kg ^ (row & 7);        // inverse-swizzled source chunk
      if (bm + row < M)
        gl16(A + (size_t)(bm + row) * K + k0 + sc * 8, &As[buf][row][kg * 8]);
      gl16(Wt + (size_t)(bn + row) * K + k0 + sc * 8, &Bs[buf][row][kg * 8]);
    }
  };
  stage(0, 0);
  int cur = 0;
  for (int k0 = 0; k0 < K; k0 += 64) {
    __syncthreads();                  // staged tile `cur` visible (vmcnt drained)
    if (k0 + 64 < K) stage(cur ^ 1, k0 + 64);   // in flight across MFMA phase
#pragma unroll
    for (int kc = 0; kc < 2; ++kc) {
      bf8v av[4], bv[4];
#pragma unroll
      for (int mi = 0; mi < 4; ++mi) {
        int row = wm * 64 + mi * 16 + l15;
        av[mi] = *(const bf8v*)&As[cur][row][((kc * 4 + l4) ^ (row & 7)) * 8];
      }
#pragma unroll
      for (int ni = 0; ni < 4; ++ni) {
        int row = wn * 64 + ni * 16 + l15;
        bv[ni] = *(const bf8v*)&Bs[cur][row][((kc * 4 + l4) ^ (row & 7)) * 8];
      }
#pragma unroll
      for (int mi = 0; mi < 4; ++mi)
#pragma unroll
        for (int ni = 0; ni < 4; ++ni)
          acc[mi][ni] = __builtin_amdgcn_mfma_f32_16x16x32_bf16(av[mi], bv[ni],
                                                                acc[mi][ni], 0, 0, 0);
    }
    cur ^= 1;
  }

#pragma unroll
  for (int mi = 0; mi < 4; ++mi) {
    int row0 = bm + wm * 64 + mi * 16 + l4 * 4;
#pragma unroll
    for (int ni = 0; ni < 4; ++ni) {
      int col = bn + wn * 64 + ni * 16 + l15;
      float bb = bias[col];
#pragma unroll
      for (int r = 0; r < 4; ++r) {
        int row = row0 + r;
        if (row < M) {
          float v = acc[mi][ni][r] + bb;
          if (relu) v = fmaxf(v, 0.f);
          C[(size_t)row * N + col] = f2bf(v);
        }
      }
    }
  }
}

// ---------------- split-K GEMM -> f32 partials (same pipeline) -------------
__global__ __launch_bounds__(256) void k_gemm_sk(const bfu* __restrict__ A,
                                                 const bfu* __restrict__ Wt,
                                                 float* __restrict__ Pf,
                                                 int M, int N, int K, int ksplit) {
  __shared__ bfu As[2][128][64];
  __shared__ bfu Bs[2][128][64];
  int z = blockIdx.z;
  int Kc = K / ksplit;
  int kbeg = z * Kc;
  Pf += (size_t)z * M * N;
  int bm = blockIdx.y * 128, bn = blockIdx.x * 128;
  int t = threadIdx.x;
  int wave = t >> 6, lane = t & 63;
  int wm = wave >> 1, wn = wave & 1;
  int l15 = lane & 15, l4 = lane >> 4;
  f32x4 acc[4][4];
  f32x4 zz = {0.f, 0.f, 0.f, 0.f};
#pragma unroll
  for (int mi = 0; mi < 4; ++mi)
#pragma unroll
    for (int ni = 0; ni < 4; ++ni) acc[mi][ni] = zz;

  auto stage = [&](int buf, int k0) {
#pragma unroll
    for (int i = 0; i < 4; ++i) {
      int c = t + i * 256;
      int row = c >> 3, kg = c & 7;
      int sc = kg ^ (row & 7);
      if (bm + row < M)
        gl16(A + (size_t)(bm + row) * K + k0 + sc * 8, &As[buf][row][kg * 8]);
      gl16(Wt + (size_t)(bn + row) * K + k0 + sc * 8, &Bs[buf][row][kg * 8]);
    }
  };
  stage(0, kbeg);
  int cur = 0;
  for (int k0 = kbeg; k0 < kbeg + Kc; k0 += 64) {
    __syncthreads();
    if (k0 + 64 < kbeg + Kc) stage(cur ^ 1, k0 + 64);
#pragma unroll
    for (int kc = 0; kc < 2; ++kc) {
      bf8v av[4], bv[4];
#pragma unroll
      for (int mi = 0; mi < 4; ++mi) {
        int row = wm * 64 + mi * 16 + l15;
        av[mi] = *(const bf8v*)&As[cur][row][((kc * 4 + l4) ^ (row & 7)) * 8];
      }
#pragma unroll
      for (int ni = 0; ni < 4; ++ni) {
        int row = wn * 64 + ni * 16 + l15;
        bv[ni] = *(const bf8v*)&Bs[cur][row][((kc * 4 + l4) ^ (row & 7)) * 8];
      }
#pragma unroll
      for (int mi = 0; mi < 4; ++mi)
#pragma unroll
        for (int ni = 0; ni < 4; ++ni)
          acc[mi][ni] = __builtin_amdgcn_mfma_f32_16x16x32_bf16(av[mi], bv[ni],
                                                                acc[mi][ni], 0, 0, 0);
    }
    cur ^= 1;
  }

#pragma unroll
  for (int mi = 0; mi < 4; ++mi) {
    int row0 = bm + wm * 64 + mi * 16 + l4 * 4;
#pragma unroll
    for (int ni = 0; ni < 4; ++ni) {
      int col = bn + wn * 64 + ni * 16 + l15;
#pragma unroll
      for (int r = 0; r < 4; ++r) {
        int row = row0 + r;
        if (row < M) Pf[(size_t)row * N + col] = acc[mi][ni][r];
      }
    }
  }
}

// ---------------- MFMA flash attention with KV reg-prefetch ----------------
__global__ __launch_bounds__(256) void k_attn_mfma(const bfu* __restrict__ Q, int qs,
                                                   const bfu* __restrict__ Km,
                                                   const bfu* __restrict__ Vm, int kvs,
                                                   bfu* __restrict__ O,
                                                   int Sq, int Sk) {
  __shared__ bfu Ks[64][72];
  __shared__ bfu Vt[64][72];       // Vt[d][kv]
  __shared__ bfu Sm[4][16][72];    // per-wave P tile
  const float scale = 0.125f;
  int b = blockIdx.z, h = blockIdx.y;
  int q0 = blockIdx.x * 64;
  int t = threadIdx.x;
  int wave = t >> 6, lane = t & 63;
  int l15 = lane & 15, l4 = lane >> 4;
  int hoff = h * 64;

  uint4 uq0 = {0u, 0u, 0u, 0u}, uq1 = {0u, 0u, 0u, 0u};
  {
    int qrow = q0 + wave * 16 + l15;
    if (qrow < Sq) {
      const bfu* qp = Q + (size_t)(b * Sq + qrow) * qs + hoff + l4 * 8;
      uq0 = *(const uint4*)qp;
      uq1 = *(const uint4*)(qp + 32);
    }
  }
  bf8v qf0 = *(bf8v*)&uq0, qf1 = *(bf8v*)&uq1;

  float m_[4] = {-1e30f, -1e30f, -1e30f, -1e30f};
  float l_[4] = {0.f, 0.f, 0.f, 0.f};
  f32x4 oacc[4];
  f32x4 zz = {0.f, 0.f, 0.f, 0.f};
#pragma unroll
  for (int n = 0; n < 4; ++n) oacc[n] = zz;

  uint4 ruk[2], ruv[2];
  const uint4 uz = {0u, 0u, 0u, 0u};
  auto load_kv = [&](int k0) {
#pragma unroll
    for (int i = 0; i < 2; ++i) {
      int e = t + i * 256;
      int rk = e >> 3, cg = e & 7;
      ruk[i] = uz;
      if (k0 + rk < Sk)
        ruk[i] = *(const uint4*)(Km + (size_t)(b * Sk + k0 + rk) * kvs + hoff + cg * 8);
      int kv = e & 63, dg = e >> 6;
      ruv[i] = uz;
      if (k0 + kv < Sk)
        ruv[i] = *(const uint4*)(Vm + (size_t)(b * Sk + k0 + kv) * kvs + hoff + dg * 8);
    }
  };
  load_kv(0);

  for (int k0 = 0; k0 < Sk; k0 += 64) {
#pragma unroll
    for (int i = 0; i < 2; ++i) {
      int e = t + i * 256;
      int rk = e >> 3, cg = e & 7;
      *(uint4*)&Ks[rk][cg * 8] = ruk[i];
      int kv = e & 63, dg = e >> 6;
      bfu vv[8];
      *(uint4*)vv = ruv[i];
#pragma unroll
      for (int j = 0; j < 8; ++j) Vt[dg * 8 + j][kv] = vv[j];
    }
    __syncthreads();  // (1) tiles ready
    if (k0 + 64 < Sk) load_kv(k0 + 64);   // prefetch next chunk

    f32x4 s4[4];
#pragma unroll
    for (int tt = 0; tt < 4; ++tt) {
      bf8v kf0 = *(const bf8v*)&Ks[tt * 16 + l15][l4 * 8];
      bf8v kf1 = *(const bf8v*)&Ks[tt * 16 + l15][32 + l4 * 8];
      f32x4 a = zz;
      a = __builtin_amdgcn_mfma_f32_16x16x32_bf16(qf0, kf0, a, 0, 0, 0);
      a = __builtin_amdgcn_mfma_f32_16x16x32_bf16(qf1, kf1, a, 0, 0, 0);
      s4[tt] = a;
    }

    float f_[4];
#pragma unroll
    for (int r = 0; r < 4; ++r) {
      float sv[4];
      float mx = -1e30f;
#pragma unroll
      for (int tt = 0; tt < 4; ++tt) {
        float s = s4[tt][r] * scale;
        s = (k0 + tt * 16 + l15 < Sk) ? s : -1e30f;
        sv[tt] = s;
        mx = fmaxf(mx, s);
      }
#pragma unroll
      for (int off = 1; off < 16; off <<= 1) mx = fmaxf(mx, __shfl_xor(mx, off));
      float nm = fmaxf(m_[r], mx);
      float f = __expf(m_[r] - nm);
      float ps = 0.f;
#pragma unroll
      for (int tt = 0; tt < 4; ++tt) {
        float p = __expf(sv[tt] - nm);
        ps += p;
        Sm[wave][l4 * 4 + r][tt * 16 + l15] = f2bf(p);
      }
#pragma unroll
      for (int off = 1; off < 16; off <<= 1) ps += __shfl_xor(ps, off);
      l_[r] = l_[r] * f + ps;
      m_[r] = nm;
      f_[r] = f;
    }
#pragma unroll
    for (int n = 0; n < 4; ++n)
#pragma unroll
      for (int r = 0; r < 4; ++r) oacc[n][r] *= f_[r];

    bf8v p0 = *(const bf8v*)&Sm[wave][l15][l4 * 8];
    bf8v p1 = *(const bf8v*)&Sm[wave][l15][32 + l4 * 8];
#pragma unroll
    for (int n = 0; n < 4; ++n) {
      bf8v v0 = *(const bf8v*)&Vt[n * 16 + l15][l4 * 8];
      bf8v v1 = *(const bf8v*)&Vt[n * 16 + l15][32 + l4 * 8];
      oacc[n] = __builtin_amdgcn_mfma_f32_16x16x32_bf16(p0, v0, oacc[n], 0, 0, 0);
      oacc[n] = __builtin_amdgcn_mfma_f32_16x16x32_bf16(p1, v1, oacc[n], 0, 0, 0);
    }
    __syncthreads();  // (2) done reading tiles
  }

#pragma unroll
  for (int r = 0; r < 4; ++r) {
    int row = q0 + wave * 16 + l4 * 4 + r;
    if (row < Sq) {
      float inv = 1.f / l_[r];
#pragma unroll
      for (int n = 0; n < 4; ++n)
        O[(size_t)(b * Sq + row) * 512 + hoff + n * 16 + l15] = f2bf(oacc[n][r] * inv);
    }
  }
}

// ---------------------------------------------------------------------------

extern "C" void kernel_launch(void* const* d_in, const int* in_sizes, int n_in,
                              void* d_out, int out_size, void* d_ws, size_t ws_size,
                              hipStream_t stream) {
  const float* src         = (const float*)d_in[0];
  const float* query_embed = (const float*)d_in[1];
  const float* pos_embed   = (const float*)d_in[2];
  const float* enc_attn_w  = (const float*)d_in[3];
  const float* enc_attn_b  = (const float*)d_in[4];
  const float* enc_w1      = (const float*)d_in[5];
  const float* enc_b1      = (const float*)d_in[6];
  const float* enc_w2      = (const float*)d_in[7];
  const float* enc_b2      = (const float*)d_in[8];
  const float* enc_ln_w    = (const float*)d_in[9];
  const float* enc_ln_b    = (const float*)d_in[10];
  const float* dec_sa_w    = (const float*)d_in[11];
  const float* dec_sa_b    = (const float*)d_in[12];
  const float* dec_ca_w    = (const float*)d_in[13];
  const float* dec_ca_b    = (const float*)d_in[14];
  const float* dec_w1      = (const float*)d_in[15];
  const float* dec_b1      = (const float*)d_in[16];
  const float* dec_w2      = (const float*)d_in[17];
  const float* dec_b2      = (const float*)d_in[18];
  const float* dec_ln_w    = (const float*)d_in[19];
  const float* dec_ln_b    = (const float*)d_in[20];
  float* out = (float*)d_out;

  const size_t ENC = 4UL * 1024 * 512;   // 2097152
  const size_t DEC = 4UL * 100 * 512;    // 204800
  const size_t MAT = 512UL * 512;        // 262144

  float* p = (float*)d_ws;
  float* x    = p; p += ENC;
  float* pos  = p; p += ENC;
  float* t1   = p; p += ENC;
  float* t2   = p; p += ENC;
  float* t3   = p; p += DEC;
  float* dstr = p; p += DEC;
  float* Pf   = p; p += 4 * ENC;   // split-K f32 partials (max 4 x 4096 x 512)

  bfu* bp = (bfu*)p;
  bfu* t1b    = bp; bp += ENC;
  bfu* t2b    = bp; bp += ENC;
  bfu* t3b    = bp; bp += DEC;
  bfu* qkvb   = bp; bp += 4096UL * 1536;
  bfu* aob    = bp; bp += ENC;
  bfu* mob    = bp; bp += ENC;
  bfu* hbb    = bp; bp += 4096UL * 2048;
  bfu* meminb = bp; bp += ENC;
  bfu* ckvb   = bp; bp += 6UL * 4096 * 1024;  // 6 layers of batched CA K/V
  // transposed bf16 weights
  bfu* enc_qkv_t = bp; bp += 18 * MAT;
  bfu* enc_out_t = bp; bp += 6 * MAT;
  bfu* enc_w1t   = bp; bp += 6UL * 512 * 2048;
  bfu* enc_w2t   = bp; bp += 6UL * 2048 * 512;
  bfu* dsa_qkv_t = bp; bp += 18 * MAT;
  bfu* dsa_out_t = bp; bp += 6 * MAT;
  bfu* dca_q_t   = bp; bp += 6 * MAT;
  bfu* dca_kv_t  = bp; bp += 12 * MAT;
  bfu* dca_out_t = bp; bp += 6 * MAT;
  bfu* dw1t      = bp; bp += 6UL * 512 * 2048;
  bfu* dw2t      = bp; bp += 6UL * 2048 * 512;

  dim3 tb(32, 8);
  k_transpose<<<dim3(16, 32, 4), tb, 0, stream>>>(src, x);
  k_transpose<<<dim3(16, 32, 4), tb, 0, stream>>>(pos_embed, pos);

  // weight conversion (once per launch)
  k_wt<<<dim3(16, 16, 18), tb, 0, stream>>>(enc_attn_w,            enc_qkv_t, 512, 512, 3, 4);
  k_wt<<<dim3(16, 16, 6),  tb, 0, stream>>>(enc_attn_w + 3 * MAT,  enc_out_t, 512, 512, 1, 4);
  k_wt<<<dim3(64, 16, 6),  tb, 0, stream>>>(enc_w1,                enc_w1t,   512, 2048, 1, 1);
  k_wt<<<dim3(16, 64, 6),  tb, 0, stream>>>(enc_w2,                enc_w2t,   2048, 512, 1, 1);
  k_wt<<<dim3(16, 16, 18), tb, 0, stream>>>(dec_sa_w,              dsa_qkv_t, 512, 512, 3, 4);
  k_wt<<<dim3(16, 16, 6),  tb, 0, stream>>>(dec_sa_w + 3 * MAT,    dsa_out_t, 512, 512, 1, 4);
  k_wt<<<dim3(16, 16, 6),  tb, 0, stream>>>(dec_ca_w,              dca_q_t,   512, 512, 1, 4);
  k_wt<<<dim3(16, 16, 12), tb, 0, stream>>>(dec_ca_w + 1 * MAT,    dca_kv_t,  512, 512, 2, 4);
  k_wt<<<dim3(16, 16, 6),  tb, 0, stream>>>(dec_ca_w + 3 * MAT,    dca_out_t, 512, 512, 1, 4);
  k_wt<<<dim3(64, 16, 6),  tb, 0, stream>>>(dec_w1,                dw1t,      512, 2048, 1, 1);
  k_wt<<<dim3(16, 64, 6),  tb, 0, stream>>>(dec_w2,                dw2t,      2048, 512, 1, 1);

  // ----------------------------- encoder ----------------------------------
  for (int l = 0; l < 6; ++l) {
    const float* ab = enc_attn_b + (size_t)l * 2048;
    float* xout = (l == 5) ? (out + DEC) : x;   // final layer writes memory output
    k_add_dual<<<2048, 256, 0, stream>>>(x, pos, t1, t1b, (int)(ENC / 4));
    k_gemm_bf<<<dim3(12, 32), 256, 0, stream>>>(t1b, enc_qkv_t + (size_t)l * 3 * MAT, ab,
                                                qkvb, 4096, 1536, 512, 0, 0, 0, 0);
    k_attn_mfma<<<dim3(16, 8, 4), 256, 0, stream>>>(qkvb, 1536, qkvb + 512, qkvb + 1024, 1536,
                                                    aob, 1024, 1024);
    k_gemm_sk<<<dim3(4, 32, 2), 256, 0, stream>>>(aob, enc_out_t + (size_t)l * MAT, Pf,
                                                  4096, 512, 512, 2);
    k_ln_red<<<1024, 256, 0, stream>>>(t1, Pf, 2, ENC, ab + 1536,
                                       enc_ln_w + (size_t)(l * 2 + 0) * 512,
                                       enc_ln_b + (size_t)(l * 2 + 0) * 512, t2, t2b, 4096);
    k_gemm_bf<<<dim3(16, 32), 256, 0, stream>>>(t2b, enc_w1t + (size_t)l * 512 * 2048,
                                                enc_b1 + (size_t)l * 2048, hbb,
                                                4096, 2048, 512, 1, 0, 0, 0);
    k_gemm_sk<<<dim3(4, 32, 4), 256, 0, stream>>>(hbb, enc_w2t + (size_t)l * 2048 * 512, Pf,
                                                  4096, 512, 2048, 4);
    k_ln_red<<<1024, 256, 0, stream>>>(t2, Pf, 4, ENC, enc_b2 + (size_t)l * 512,
                                       enc_ln_w + (size_t)(l * 2 + 1) * 512,
                                       enc_ln_b + (size_t)(l * 2 + 1) * 512,
                                       xout, (bfu*)nullptr, 4096);
  }

  k_add_dual<<<2048, 256, 0, stream>>>(out + DEC, pos, (float*)nullptr, meminb, (int)(ENC / 4));
  k_zero<<<200, 256, 0, stream>>>(dstr, (int)(DEC / 4));

  // all 6 decoder layers' cross-attn K/V projections in one dispatch
  k_gemm_bf<<<dim3(8, 32, 6), 256, 0, stream>>>(meminb, dca_kv_t, dec_ca_b + 512,
                                                ckvb, 4096, 1024, 512, 0,
                                                2 * MAT, 4096UL * 1024, 2048);

  // ----------------------------- decoder ----------------------------------
  for (int l = 0; l < 6; ++l) {
    const float* sb = dec_sa_b + (size_t)l * 2048;
    const float* cb = dec_ca_b + (size_t)l * 2048;
    float* dout = (l == 5) ? out : dstr;
    k_add_qe_dual<<<200, 256, 0, stream>>>(dstr, query_embed, t1, t1b);
    // self-attention
    k_gemm_bf<<<dim3(12, 4), 256, 0, stream>>>(t1b, dsa_qkv_t + (size_t)l * 3 * MAT, sb,
                                               qkvb, 400, 1536, 512, 0, 0, 0, 0);
    k_attn_mfma<<<dim3(2, 8, 4), 256, 0, stream>>>(qkvb, 1536, qkvb + 512, qkvb + 1024, 1536,
                                                   aob, 100, 100);
    k_gemm_sk<<<dim3(4, 4, 2), 256, 0, stream>>>(aob, dsa_out_t + (size_t)l * MAT, Pf,
                                                 400, 512, 512, 2);
    k_ln_red<<<100, 256, 0, stream>>>(t1, Pf, 2, 400UL * 512, sb + 1536,
                                      dec_ln_w + (size_t)(l * 3 + 0) * 512,
                                      dec_ln_b + (size_t)(l * 3 + 0) * 512, t2, t2b, 400);
    // cross-attention
    k_gemm_bf<<<dim3(4, 4), 256, 0, stream>>>(t2b, dca_q_t + (size_t)l * MAT, cb,
                                              qkvb, 400, 512, 512, 0, 0, 0, 0);
    k_attn_mfma<<<dim3(2, 8, 4), 256, 0, stream>>>(qkvb, 512,
                                                   ckvb + (size_t)l * 4096 * 1024,
                                                   ckvb + (size_t)l * 4096 * 1024 + 512, 1024,
                                                   aob, 100, 1024);
    k_gemm_sk<<<dim3(4, 4, 2), 256, 0, stream>>>(aob, dca_out_t + (size_t)l * MAT, Pf,
                                                 400, 512, 512, 2);
    k_ln_red<<<100, 256, 0, stream>>>(t2, Pf, 2, 400UL * 512, cb + 1536,
                                      dec_ln_w + (size_t)(l * 3 + 1) * 512,
                                      dec_ln_b + (size_t)(l * 3 + 1) * 512, t3, t3b, 400);
    // ffn
    k_gemm_bf<<<dim3(16, 4), 256, 0, stream>>>(t3b, dw1t + (size_t)l * 512 * 2048,
                                               dec_b1 + (size_t)l * 2048, hbb,
                                               400, 2048, 512, 1, 0, 0, 0);
    k_gemm_sk<<<dim3(4, 4, 4), 256, 0, stream>>>(hbb, dw2t + (size_t)l * 2048 * 512, Pf,
                                                 400, 512, 2048, 4);
    k_ln_red<<<100, 256, 0, stream>>>(t3, Pf, 4, 400UL * 512, dec_b2 + (size_t)l * 512,
                                      dec_ln_w + (size_t)(l * 3 + 2) * 512,
                                      dec_ln_b + (size_t)(l * 3 + 2) * 512,
                                      dout, (bfu*)nullptr, 400);
  }
}

// Round 7
// 1996.572 us; speedup vs baseline: 8.8897x; 1.0187x over previous
//
#include <hip/hip_runtime.h>
#include <math.h>

// ---------------------------------------------------------------------------
// DETR-style transformer. bf16 MFMA GEMMs (global_load_lds, 2-phase dbuf,
// XOR-swizzled LDS) + bf16 MFMA flash attention (KVBLK=128, setprio).
// LN kernels fuse split-K reduce + residual + (pos|query_embed) re-add.
// B=4, S=1024, NQ=100, D=512, H=8, dk=64, FF=2048, L=6
// ---------------------------------------------------------------------------

typedef unsigned short bfu;
typedef unsigned int u32;
typedef __bf16 bf8v __attribute__((ext_vector_type(8)));
typedef float f32x4 __attribute__((ext_vector_type(4)));

__device__ inline bfu f2bf(float f) {
  union { float f; u32 u; } v; v.f = f;
  u32 u = v.u;
  u32 r = (u + 0x7fffu + ((u >> 16) & 1u)) >> 16;
  return (bfu)r;
}
__device__ inline float bflo(u32 u) { return __uint_as_float(u << 16); }

// async global->LDS, 16 bytes per lane (wave-uniform LDS base + lane*16)
typedef const __attribute__((address_space(1))) u32 gas_t;
typedef __attribute__((address_space(3))) u32 las_t;
__device__ __forceinline__ void gl16(const void* g, void* l) {
  __builtin_amdgcn_global_load_lds((gas_t*)g, (las_t*)l, 16, 0, 0);
}

// ---------------- transpose f32 [B][C][S] -> [B][S][C] ----------------------
__global__ __launch_bounds__(256) void k_transpose(const float* __restrict__ in,
                                                   float* __restrict__ out) {
  __shared__ float tile[32][33];
  int b = blockIdx.z;
  int c0 = blockIdx.x * 32, s0 = blockIdx.y * 32;
  int tx = threadIdx.x, ty = threadIdx.y;  // (32, 8)
  for (int i = ty; i < 32; i += 8)
    tile[i][tx] = in[((size_t)(b * 512 + c0 + i)) * 1024 + s0 + tx];
  __syncthreads();
  for (int i = ty; i < 32; i += 8)
    out[((size_t)(b * 1024 + s0 + i)) * 512 + c0 + tx] = tile[tx][i];
}

// ---------------- weight transpose+convert: src f32 [K][N] -> dst bf16 [N][K]
__global__ __launch_bounds__(256) void k_wt(const float* __restrict__ src,
                                            bfu* __restrict__ dst,
                                            int K, int N, int nj, int lstride) {
  __shared__ bfu tile[32][33];
  int g = blockIdx.z;
  int l = g / nj, j = g - l * nj;
  const float* s = src + ((size_t)l * lstride + j) * (size_t)K * N;
  bfu* d = dst + (size_t)g * (size_t)K * N;
  int n0 = blockIdx.x * 32, k0 = blockIdx.y * 32;
  int tx = threadIdx.x, ty = threadIdx.y;  // (32, 8)
  for (int i = ty; i < 32; i += 8)
    tile[i][tx] = f2bf(s[(size_t)(k0 + i) * N + n0 + tx]);
  __syncthreads();
  for (int i = ty; i < 32; i += 8)
    d[(size_t)(n0 + i) * K + k0 + tx] = tile[tx][i];
}

// ---------------- encoder layer-0 input: t1 = x + pos (f32 + bf16) ---------
__global__ void k_add_dual(const float* __restrict__ a, const float* __restrict__ b,
                           float* __restrict__ of, bfu* __restrict__ ob, int n4) {
  int i = blockIdx.x * blockDim.x + threadIdx.x;
  if (i >= n4) return;
  float4 x = ((const float4*)a)[i];
  float4 y = ((const float4*)b)[i];
  float4 r = make_float4(x.x + y.x, x.y + y.y, x.z + y.z, x.w + y.w);
  ((float4*)of)[i] = r;
  ((ushort4*)ob)[i] = make_ushort4(f2bf(r.x), f2bf(r.y), f2bf(r.z), f2bf(r.w));
}

// ---------------- decoder layer-0 input: t1 = qe broadcast -----------------
__global__ void k_qe0(const float* __restrict__ qe, float* __restrict__ of,
                      bfu* __restrict__ ob) {
  int i = blockIdx.x * blockDim.x + threadIdx.x;
  if (i >= 51200) return;
  int row = i >> 7;
  int q = row % 100;
  int c4 = i & 127;
  float4 y = ((const float4*)qe)[q * 128 + c4];
  ((float4*)of)[i] = y;
  ((ushort4*)ob)[i] = make_ushort4(f2bf(y.x), f2bf(y.y), f2bf(y.z), f2bf(y.w));
}

// ---------------- LN(A + sum_z P[z] + bias), fused epilogues ---------------
// o = LN(...)*g + be ; writes optional {of, ob} = o and {of2, ob2} = o + add2
// qe_mode: 0 -> add2 indexed by row, 1 -> add2 indexed by row%100.
__global__ __launch_bounds__(256) void k_ln_red(const float* __restrict__ A,
                                                const float* __restrict__ P,
                                                int nsplit, size_t pz,
                                                const float* __restrict__ bias,
                                                const float* __restrict__ g,
                                                const float* __restrict__ be,
                                                float* __restrict__ of,
                                                bfu* __restrict__ ob,
                                                const float* __restrict__ add2,
                                                int qe_mode,
                                                float* __restrict__ of2,
                                                bfu* __restrict__ ob2,
                                                int rows) {
  int row = blockIdx.x * 4 + (threadIdx.x >> 6);
  int lane = threadIdx.x & 63;
  if (row >= rows) return;
  const float* pa = A + (size_t)row * 512;
  float v[8];
  float s = 0.f, s2 = 0.f;
#pragma unroll
  for (int j = 0; j < 8; ++j) {
    int c = lane + j * 64;
    float x = pa[c] + bias[c];
    for (int z = 0; z < nsplit; ++z) x += P[z * pz + (size_t)row * 512 + c];
    v[j] = x; s += x; s2 += x * x;
  }
#pragma unroll
  for (int off = 32; off > 0; off >>= 1) {
    s += __shfl_xor(s, off);
    s2 += __shfl_xor(s2, off);
  }
  float mean = s * (1.f / 512.f);
  float var = s2 * (1.f / 512.f) - mean * mean;
  float r = rsqrtf(var + 1e-5f);
  int arow = qe_mode ? (row % 100) : row;
#pragma unroll
  for (int j = 0; j < 8; ++j) {
    int c = lane + j * 64;
    float o = (v[j] - mean) * r * g[c] + be[c];
    if (of) of[(size_t)row * 512 + c] = o;
    if (ob) ob[(size_t)row * 512 + c] = f2bf(o);
    if (add2) {
      float o2 = o + add2[(size_t)arow * 512 + c];
      if (of2) of2[(size_t)row * 512 + c] = o2;
      if (ob2) ob2[(size_t)row * 512 + c] = f2bf(o2);
    }
  }
}

// ---------------- bf16 MFMA GEMM: global_load_lds + 2-phase double buffer --
__global__ __launch_bounds__(256) void k_gemm_bf(const bfu* __restrict__ A,
                                                 const bfu* __restrict__ Wt,
                                                 const float* __restrict__ bias,
                                                 bfu* __restrict__ C,
                                                 int M, int N, int K, int relu,
                                                 size_t wtz, size_t cz, int bz) {
  __shared__ bfu As[2][128][64];
  __shared__ bfu Bs[2][128][64];
  int z = blockIdx.z;
  Wt += (size_t)z * wtz; C += (size_t)z * cz; bias += z * bz;
  int bm = blockIdx.y * 128, bn = blockIdx.x * 128;
  int t = threadIdx.x;
  int wave = t >> 6, lane = t & 63;
  int wm = wave >> 1, wn = wave & 1;
  int l15 = lane & 15, l4 = lane >> 4;
  f32x4 acc[4][4];
  f32x4 zz = {0.f, 0.f, 0.f, 0.f};
#pragma unroll
  for (int mi = 0; mi < 4; ++mi)
#pragma unroll
    for (int ni = 0; ni < 4; ++ni) acc[mi][ni] = zz;

  auto stage = [&](int buf, int k0) {
#pragma unroll
    for (int i = 0; i < 4; ++i) {
      int c = t + i * 256;            // 0..1023 chunks of 16B
      int row = c >> 3, kg = c & 7;
      int sc = kg ^ (row & 7);        // inverse-swizzled source chunk
      if (bm + row < M)
        gl16(A + (size_t)(bm + row) * K + k0 + sc * 8, &As[buf][row][kg * 8]);
      gl16(Wt + (size_t)(bn + row) * K + k0 + sc * 8, &Bs[buf][row][kg * 8]);
    }
  };
  stage(0, 0);
  int cur = 0;
  for (int k0 = 0; k0 < K; k0 += 64) {
    __syncthreads();                  // staged tile `cur` visible
    if (k0 + 64 < K) stage(cur ^ 1, k0 + 64);
#pragma unroll
    for (int kc = 0; kc < 2; ++kc) {
      bf8v av[4], bv[4];
#pragma unroll
      for (int mi = 0; mi < 4; ++mi) {
        int row = wm * 64 + mi * 16 + l15;
        av[mi] = *(const bf8v*)&As[cur][row][((kc * 4 + l4) ^ (row & 7)) * 8];
      }
#pragma unroll
      for (int ni = 0; ni < 4; ++ni) {
        int row = wn * 64 + ni * 16 + l15;
        bv[ni] = *(const bf8v*)&Bs[cur][row][((kc * 4 + l4) ^ (row & 7)) * 8];
      }
#pragma unroll
      for (int mi = 0; mi < 4; ++mi)
#pragma unroll
        for (int ni = 0; ni < 4; ++ni)
          acc[mi][ni] = __builtin_amdgcn_mfma_f32_16x16x32_bf16(av[mi], bv[ni],
                                                                acc[mi][ni], 0, 0, 0);
    }
    cur ^= 1;
  }

#pragma unroll
  for (int mi = 0; mi < 4; ++mi) {
    int row0 = bm + wm * 64 + mi * 16 + l4 * 4;
#pragma unroll
    for (int ni = 0; ni < 4; ++ni) {
      int col = bn + wn * 64 + ni * 16 + l15;
      float bb = bias[col];
#pragma unroll
      for (int r = 0; r < 4; ++r) {
        int row = row0 + r;
        if (row < M) {
          float v = acc[mi][ni][r] + bb;
          if (relu) v = fmaxf(v, 0.f);
          C[(size_t)row * N + col] = f2bf(v);
        }
      }
    }
  }
}

// ---------------- split-K GEMM -> f32 partials (same pipeline) -------------
__global__ __launch_bounds__(256) void k_gemm_sk(const bfu* __restrict__ A,
                                                 const bfu* __restrict__ Wt,
                                                 float* __restrict__ Pf,
                                                 int M, int N, int K, int ksplit) {
  __shared__ bfu As[2][128][64];
  __shared__ bfu Bs[2][128][64];
  int z = blockIdx.z;
  int Kc = K / ksplit;
  int kbeg = z * Kc;
  Pf += (size_t)z * M * N;
  int bm = blockIdx.y * 128, bn = blockIdx.x * 128;
  int t = threadIdx.x;
  int wave = t >> 6, lane = t & 63;
  int wm = wave >> 1, wn = wave & 1;
  int l15 = lane & 15, l4 = lane >> 4;
  f32x4 acc[4][4];
  f32x4 zz = {0.f, 0.f, 0.f, 0.f};
#pragma unroll
  for (int mi = 0; mi < 4; ++mi)
#pragma unroll
    for (int ni = 0; ni < 4; ++ni) acc[mi][ni] = zz;

  auto stage = [&](int buf, int k0) {
#pragma unroll
    for (int i = 0; i < 4; ++i) {
      int c = t + i * 256;
      int row = c >> 3, kg = c & 7;
      int sc = kg ^ (row & 7);
      if (bm + row < M)
        gl16(A + (size_t)(bm + row) * K + k0 + sc * 8, &As[buf][row][kg * 8]);
      gl16(Wt + (size_t)(bn + row) * K + k0 + sc * 8, &Bs[buf][row][kg * 8]);
    }
  };
  stage(0, kbeg);
  int cur = 0;
  for (int k0 = kbeg; k0 < kbeg + Kc; k0 += 64) {
    __syncthreads();
    if (k0 + 64 < kbeg + Kc) stage(cur ^ 1, k0 + 64);
#pragma unroll
    for (int kc = 0; kc < 2; ++kc) {
      bf8v av[4], bv[4];
#pragma unroll
      for (int mi = 0; mi < 4; ++mi) {
        int row = wm * 64 + mi * 16 + l15;
        av[mi] = *(const bf8v*)&As[cur][row][((kc * 4 + l4) ^ (row & 7)) * 8];
      }
#pragma unroll
      for (int ni = 0; ni < 4; ++ni) {
        int row = wn * 64 + ni * 16 + l15;
        bv[ni] = *(const bf8v*)&Bs[cur][row][((kc * 4 + l4) ^ (row & 7)) * 8];
      }
#pragma unroll
      for (int mi = 0; mi < 4; ++mi)
#pragma unroll
        for (int ni = 0; ni < 4; ++ni)
          acc[mi][ni] = __builtin_amdgcn_mfma_f32_16x16x32_bf16(av[mi], bv[ni],
                                                                acc[mi][ni], 0, 0, 0);
    }
    cur ^= 1;
  }

#pragma unroll
  for (int mi = 0; mi < 4; ++mi) {
    int row0 = bm + wm * 64 + mi * 16 + l4 * 4;
#pragma unroll
    for (int ni = 0; ni < 4; ++ni) {
      int col = bn + wn * 64 + ni * 16 + l15;
#pragma unroll
      for (int r = 0; r < 4; ++r) {
        int row = row0 + r;
        if (row < M) Pf[(size_t)row * N + col] = acc[mi][ni][r];
      }
    }
  }
}

// ---------------- MFMA flash attention, KVBLK=128, reg-prefetch ------------
// 256 thr = 4 waves; wave w owns q-rows [q0+16w, q0+16w+16).
__global__ __launch_bounds__(256) void k_attn_mfma(const bfu* __restrict__ Q, int qs,
                                                   const bfu* __restrict__ Km,
                                                   const bfu* __restrict__ Vm, int kvs,
                                                   bfu* __restrict__ O,
                                                   int Sq, int Sk) {
  __shared__ bfu Ks[128][72];
  __shared__ bfu Vt[64][136];      // Vt[d][kv] for 128 kv
  __shared__ bfu Sm[4][16][136];   // per-wave P tile (128 wide)
  const float scale = 0.125f;
  int b = blockIdx.z, h = blockIdx.y;
  int q0 = blockIdx.x * 64;
  int t = threadIdx.x;
  int wave = t >> 6, lane = t & 63;
  int l15 = lane & 15, l4 = lane >> 4;
  int hoff = h * 64;

  uint4 uq0 = {0u, 0u, 0u, 0u}, uq1 = {0u, 0u, 0u, 0u};
  {
    int qrow = q0 + wave * 16 + l15;
    if (qrow < Sq) {
      const bfu* qp = Q + (size_t)(b * Sq + qrow) * qs + hoff + l4 * 8;
      uq0 = *(const uint4*)qp;
      uq1 = *(const uint4*)(qp + 32);
    }
  }
  bf8v qf0 = *(bf8v*)&uq0, qf1 = *(bf8v*)&uq1;

  float m_[4] = {-1e30f, -1e30f, -1e30f, -1e30f};
  float l_[4] = {0.f, 0.f, 0.f, 0.f};
  f32x4 oacc[4];
  f32x4 zz = {0.f, 0.f, 0.f, 0.f};
#pragma unroll
  for (int n = 0; n < 4; ++n) oacc[n] = zz;

  uint4 ruk[4], ruv[4];
  const uint4 uz = {0u, 0u, 0u, 0u};
  auto load_kv = [&](int k0) {
#pragma unroll
    for (int i = 0; i < 4; ++i) {
      int e = t + i * 256;                 // 0..1023
      int rk = e >> 3, cg = e & 7;         // K: 128 rows x 8 chunks
      ruk[i] = uz;
      if (k0 + rk < Sk)
        ruk[i] = *(const uint4*)(Km + (size_t)(b * Sk + k0 + rk) * kvs + hoff + cg * 8);
      int kv = e & 127, dg = e >> 7;       // V: 128 kv x 8 dgroups
      ruv[i] = uz;
      if (k0 + kv < Sk)
        ruv[i] = *(const uint4*)(Vm + (size_t)(b * Sk + k0 + kv) * kvs + hoff + dg * 8);
    }
  };
  load_kv(0);

  for (int k0 = 0; k0 < Sk; k0 += 128) {
#pragma unroll
    for (int i = 0; i < 4; ++i) {
      int e = t + i * 256;
      int rk = e >> 3, cg = e & 7;
      *(uint4*)&Ks[rk][cg * 8] = ruk[i];
      int kv = e & 127, dg = e >> 7;
      bfu vv[8];
      *(uint4*)vv = ruv[i];
#pragma unroll
      for (int j = 0; j < 8; ++j) Vt[dg * 8 + j][kv] = vv[j];
    }
    __syncthreads();  // (1) tiles ready
    if (k0 + 128 < Sk) load_kv(k0 + 128);   // prefetch next chunk

    // S = Q K^T : 8 kv-tiles of 16
    f32x4 s4[8];
    __builtin_amdgcn_s_setprio(1);
#pragma unroll
    for (int tt = 0; tt < 8; ++tt) {
      bf8v kf0 = *(const bf8v*)&Ks[tt * 16 + l15][l4 * 8];
      bf8v kf1 = *(const bf8v*)&Ks[tt * 16 + l15][32 + l4 * 8];
      f32x4 a = zz;
      a = __builtin_amdgcn_mfma_f32_16x16x32_bf16(qf0, kf0, a, 0, 0, 0);
      a = __builtin_amdgcn_mfma_f32_16x16x32_bf16(qf1, kf1, a, 0, 0, 0);
      s4[tt] = a;
    }
    __builtin_amdgcn_s_setprio(0);

    // online softmax; lane sees q-rows l4*4+r, kv cols tt*16+l15
    float f_[4];
#pragma unroll
    for (int r = 0; r < 4; ++r) {
      float sv[8];
      float mx = -1e30f;
#pragma unroll
      for (int tt = 0; tt < 8; ++tt) {
        float s = s4[tt][r] * scale;
        s = (k0 + tt * 16 + l15 < Sk) ? s : -1e30f;
        sv[tt] = s;
        mx = fmaxf(mx, s);
      }
#pragma unroll
      for (int off = 1; off < 16; off <<= 1) mx = fmaxf(mx, __shfl_xor(mx, off));
      float nm = fmaxf(m_[r], mx);
      float f = __expf(m_[r] - nm);
      float ps = 0.f;
#pragma unroll
      for (int tt = 0; tt < 8; ++tt) {
        float p = __expf(sv[tt] - nm);
        ps += p;
        Sm[wave][l4 * 4 + r][tt * 16 + l15] = f2bf(p);
      }
#pragma unroll
      for (int off = 1; off < 16; off <<= 1) ps += __shfl_xor(ps, off);
      l_[r] = l_[r] * f + ps;
      m_[r] = nm;
      f_[r] = f;
    }
#pragma unroll
    for (int n = 0; n < 4; ++n)
#pragma unroll
      for (int r = 0; r < 4; ++r) oacc[n][r] *= f_[r];

    // O += P V over two 64-kv halves
    __builtin_amdgcn_s_setprio(1);
#pragma unroll
    for (int h2 = 0; h2 < 2; ++h2) {
      bf8v p0 = *(const bf8v*)&Sm[wave][l15][h2 * 64 + l4 * 8];
      bf8v p1 = *(const bf8v*)&Sm[wave][l15][h2 * 64 + 32 + l4 * 8];
#pragma unroll
      for (int n = 0; n < 4; ++n) {
        bf8v v0 = *(const bf8v*)&Vt[n * 16 + l15][h2 * 64 + l4 * 8];
        bf8v v1 = *(const bf8v*)&Vt[n * 16 + l15][h2 * 64 + 32 + l4 * 8];
        oacc[n] = __builtin_amdgcn_mfma_f32_16x16x32_bf16(p0, v0, oacc[n], 0, 0, 0);
        oacc[n] = __builtin_amdgcn_mfma_f32_16x16x32_bf16(p1, v1, oacc[n], 0, 0, 0);
      }
    }
    __builtin_amdgcn_s_setprio(0);
    __syncthreads();  // (2) done reading tiles
  }

#pragma unroll
  for (int r = 0; r < 4; ++r) {
    int row = q0 + wave * 16 + l4 * 4 + r;
    if (row < Sq) {
      float inv = 1.f / l_[r];
#pragma unroll
      for (int n = 0; n < 4; ++n)
        O[(size_t)(b * Sq + row) * 512 + hoff + n * 16 + l15] = f2bf(oacc[n][r] * inv);
    }
  }
}

// ---------------------------------------------------------------------------

extern "C" void kernel_launch(void* const* d_in, const int* in_sizes, int n_in,
                              void* d_out, int out_size, void* d_ws, size_t ws_size,
                              hipStream_t stream) {
  const float* src         = (const float*)d_in[0];
  const float* query_embed = (const float*)d_in[1];
  const float* pos_embed   = (const float*)d_in[2];
  const float* enc_attn_w  = (const float*)d_in[3];
  const float* enc_attn_b  = (const float*)d_in[4];
  const float* enc_w1      = (const float*)d_in[5];
  const float* enc_b1      = (const float*)d_in[6];
  const float* enc_w2      = (const float*)d_in[7];
  const float* enc_b2      = (const float*)d_in[8];
  const float* enc_ln_w    = (const float*)d_in[9];
  const float* enc_ln_b    = (const float*)d_in[10];
  const float* dec_sa_w    = (const float*)d_in[11];
  const float* dec_sa_b    = (const float*)d_in[12];
  const float* dec_ca_w    = (const float*)d_in[13];
  const float* dec_ca_b    = (const float*)d_in[14];
  const float* dec_w1      = (const float*)d_in[15];
  const float* dec_b1      = (const float*)d_in[16];
  const float* dec_w2      = (const float*)d_in[17];
  const float* dec_b2      = (const float*)d_in[18];
  const float* dec_ln_w    = (const float*)d_in[19];
  const float* dec_ln_b    = (const float*)d_in[20];
  float* out = (float*)d_out;

  const size_t ENC = 4UL * 1024 * 512;   // 2097152
  const size_t DEC = 4UL * 100 * 512;    // 204800
  const size_t MAT = 512UL * 512;        // 262144

  float* p = (float*)d_ws;
  float* x    = p; p += ENC;
  float* pos  = p; p += ENC;
  float* t1   = p; p += ENC;
  float* t2   = p; p += ENC;
  float* t3   = p; p += DEC;
  float* Pf   = p; p += 4 * ENC;   // split-K f32 partials (max 4 x 4096 x 512)

  bfu* bp = (bfu*)p;
  bfu* t1b    = bp; bp += ENC;
  bfu* t2b    = bp; bp += ENC;
  bfu* t3b    = bp; bp += DEC;
  bfu* qkvb   = bp; bp += 4096UL * 1536;
  bfu* aob    = bp; bp += ENC;
  bfu* hbb    = bp; bp += 4096UL * 2048;
  bfu* meminb = bp; bp += ENC;
  bfu* ckvb   = bp; bp += 6UL * 4096 * 1024;  // 6 layers of batched CA K/V
  // transposed bf16 weights
  bfu* enc_qkv_t = bp; bp += 18 * MAT;
  bfu* enc_out_t = bp; bp += 6 * MAT;
  bfu* enc_w1t   = bp; bp += 6UL * 512 * 2048;
  bfu* enc_w2t   = bp; bp += 6UL * 2048 * 512;
  bfu* dsa_qkv_t = bp; bp += 18 * MAT;
  bfu* dsa_out_t = bp; bp += 6 * MAT;
  bfu* dca_q_t   = bp; bp += 6 * MAT;
  bfu* dca_kv_t  = bp; bp += 12 * MAT;
  bfu* dca_out_t = bp; bp += 6 * MAT;
  bfu* dw1t      = bp; bp += 6UL * 512 * 2048;
  bfu* dw2t      = bp; bp += 6UL * 2048 * 512;

  dim3 tb(32, 8);
  k_transpose<<<dim3(16, 32, 4), tb, 0, stream>>>(src, x);
  k_transpose<<<dim3(16, 32, 4), tb, 0, stream>>>(pos_embed, pos);

  // weight conversion (once per launch)
  k_wt<<<dim3(16, 16, 18), tb, 0, stream>>>(enc_attn_w,            enc_qkv_t, 512, 512, 3, 4);
  k_wt<<<dim3(16, 16, 6),  tb, 0, stream>>>(enc_attn_w + 3 * MAT,  enc_out_t, 512, 512, 1, 4);
  k_wt<<<dim3(64, 16, 6),  tb, 0, stream>>>(enc_w1,                enc_w1t,   512, 2048, 1, 1);
  k_wt<<<dim3(16, 64, 6),  tb, 0, stream>>>(enc_w2,                enc_w2t,   2048, 512, 1, 1);
  k_wt<<<dim3(16, 16, 18), tb, 0, stream>>>(dec_sa_w,              dsa_qkv_t, 512, 512, 3, 4);
  k_wt<<<dim3(16, 16, 6),  tb, 0, stream>>>(dec_sa_w + 3 * MAT,    dsa_out_t, 512, 512, 1, 4);
  k_wt<<<dim3(16, 16, 6),  tb, 0, stream>>>(dec_ca_w,              dca_q_t,   512, 512, 1, 4);
  k_wt<<<dim3(16, 16, 12), tb, 0, stream>>>(dec_ca_w + 1 * MAT,    dca_kv_t,  512, 512, 2, 4);
  k_wt<<<dim3(16, 16, 6),  tb, 0, stream>>>(dec_ca_w + 3 * MAT,    dca_out_t, 512, 512, 1, 4);
  k_wt<<<dim3(64, 16, 6),  tb, 0, stream>>>(dec_w1,                dw1t,      512, 2048, 1, 1);
  k_wt<<<dim3(16, 64, 6),  tb, 0, stream>>>(dec_w2,                dw2t,      2048, 512, 1, 1);

  // ----------------------------- encoder ----------------------------------
  k_add_dual<<<2048, 256, 0, stream>>>(x, pos, t1, t1b, (int)(ENC / 4));
  for (int l = 0; l < 6; ++l) {
    const float* ab = enc_attn_b + (size_t)l * 2048;
    k_gemm_bf<<<dim3(12, 32), 256, 0, stream>>>(t1b, enc_qkv_t + (size_t)l * 3 * MAT, ab,
                                                qkvb, 4096, 1536, 512, 0, 0, 0, 0);
    k_attn_mfma<<<dim3(16, 8, 4), 256, 0, stream>>>(qkvb, 1536, qkvb + 512, qkvb + 1024, 1536,
                                                    aob, 1024, 1024);
    k_gemm_sk<<<dim3(4, 32, 2), 256, 0, stream>>>(aob, enc_out_t + (size_t)l * MAT, Pf,
                                                  4096, 512, 512, 2);
    // t2 = LN(t1 + proj), dual f32/bf16
    k_ln_red<<<1024, 256, 0, stream>>>(t1, Pf, 2, ENC, ab + 1536,
                                       enc_ln_w + (size_t)(l * 2 + 0) * 512,
                                       enc_ln_b + (size_t)(l * 2 + 0) * 512,
                                       t2, t2b, (const float*)nullptr, 0,
                                       (float*)nullptr, (bfu*)nullptr, 4096);
    k_gemm_bf<<<dim3(16, 32), 256, 0, stream>>>(t2b, enc_w1t + (size_t)l * 512 * 2048,
                                                enc_b1 + (size_t)l * 2048, hbb,
                                                4096, 2048, 512, 1, 0, 0, 0);
    k_gemm_sk<<<dim3(4, 32, 4), 256, 0, stream>>>(hbb, enc_w2t + (size_t)l * 2048 * 512, Pf,
                                                  4096, 512, 2048, 4);
    // x_new = LN(t2 + ffn); next-layer t1 = x_new + pos (fused)
    if (l < 5) {
      k_ln_red<<<1024, 256, 0, stream>>>(t2, Pf, 4, ENC, enc_b2 + (size_t)l * 512,
                                         enc_ln_w + (size_t)(l * 2 + 1) * 512,
                                         enc_ln_b + (size_t)(l * 2 + 1) * 512,
                                         (float*)nullptr, (bfu*)nullptr,
                                         pos, 0, t1, t1b, 4096);
    } else {
      // memory output (f32) + meminb = bf16(memory + pos)
      k_ln_red<<<1024, 256, 0, stream>>>(t2, Pf, 4, ENC, enc_b2 + (size_t)l * 512,
                                         enc_ln_w + (size_t)(l * 2 + 1) * 512,
                                         enc_ln_b + (size_t)(l * 2 + 1) * 512,
                                         out + DEC, (bfu*)nullptr,
                                         pos, 0, (float*)nullptr, meminb, 4096);
    }
  }

  // all 6 decoder layers' cross-attn K/V projections in one dispatch
  k_gemm_bf<<<dim3(8, 32, 6), 256, 0, stream>>>(meminb, dca_kv_t, dec_ca_b + 512,
                                                ckvb, 4096, 1024, 512, 0,
                                                2 * MAT, 4096UL * 1024, 2048);

  // ----------------------------- decoder ----------------------------------
  k_qe0<<<200, 256, 0, stream>>>(query_embed, t1, t1b);
  for (int l = 0; l < 6; ++l) {
    const float* sb = dec_sa_b + (size_t)l * 2048;
    const float* cb = dec_ca_b + (size_t)l * 2048;
    // self-attention
    k_gemm_bf<<<dim3(12, 4), 256, 0, stream>>>(t1b, dsa_qkv_t + (size_t)l * 3 * MAT, sb,
                                               qkvb, 400, 1536, 512, 0, 0, 0, 0);
    k_attn_mfma<<<dim3(2, 8, 4), 256, 0, stream>>>(qkvb, 1536, qkvb + 512, qkvb + 1024, 1536,
                                                   aob, 100, 100);
    k_gemm_sk<<<dim3(4, 4, 2), 256, 0, stream>>>(aob, dsa_out_t + (size_t)l * MAT, Pf,
                                                 400, 512, 512, 2);
    k_ln_red<<<100, 256, 0, stream>>>(t1, Pf, 2, 400UL * 512, sb + 1536,
                                      dec_ln_w + (size_t)(l * 3 + 0) * 512,
                                      dec_ln_b + (size_t)(l * 3 + 0) * 512,
                                      t2, t2b, (const float*)nullptr, 0,
                                      (float*)nullptr, (bfu*)nullptr, 400);
    // cross-attention
    k_gemm_bf<<<dim3(4, 4), 256, 0, stream>>>(t2b, dca_q_t + (size_t)l * MAT, cb,
                                              qkvb, 400, 512, 512, 0, 0, 0, 0);
    k_attn_mfma<<<dim3(2, 8, 4), 256, 0, stream>>>(qkvb, 512,
                                                   ckvb + (size_t)l * 4096 * 1024,
                                                   ckvb + (size_t)l * 4096 * 1024 + 512, 1024,
                                                   aob, 100, 1024);
    k_gemm_sk<<<dim3(4, 4, 2), 256, 0, stream>>>(aob, dca_out_t + (size_t)l * MAT, Pf,
                                                 400, 512, 512, 2);
    k_ln_red<<<100, 256, 0, stream>>>(t2, Pf, 2, 400UL * 512, cb + 1536,
                                      dec_ln_w + (size_t)(l * 3 + 1) * 512,
                                      dec_ln_b + (size_t)(l * 3 + 1) * 512,
                                      t3, t3b, (const float*)nullptr, 0,
                                      (float*)nullptr, (bfu*)nullptr, 400);
    // ffn
    k_gemm_bf<<<dim3(16, 4), 256, 0, stream>>>(t3b, dw1t + (size_t)l * 512 * 2048,
                                               dec_b1 + (size_t)l * 2048, hbb,
                                               400, 2048, 512, 1, 0, 0, 0);
    k_gemm_sk<<<dim3(4, 4, 4), 256, 0, stream>>>(hbb, dw2t + (size_t)l * 2048 * 512, Pf,
                                                 400, 512, 2048, 4);
    if (l < 5) {
      // next-layer t1 = LN(t3 + ffn) + qe (fused)
      k_ln_red<<<100, 256, 0, stream>>>(t3, Pf, 4, 400UL * 512, dec_b2 + (size_t)l * 512,
                                        dec_ln_w + (size_t)(l * 3 + 2) * 512,
                                        dec_ln_b + (size_t)(l * 3 + 2) * 512,
                                        (float*)nullptr, (bfu*)nullptr,
                                        query_embed, 1, t1, t1b, 400);
    } else {
      k_ln_red<<<100, 256, 0, stream>>>(t3, Pf, 4, 400UL * 512, dec_b2 + (size_t)l * 512,
                                        dec_ln_w + (size_t)(l * 3 + 2) * 512,
                                        dec_ln_b + (size_t)(l * 3 + 2) * 512,
                                        out, (bfu*)nullptr,
                                        (const float*)nullptr, 0,
                                        (float*)nullptr, (bfu*)nullptr, 400);
    }
  }
}